// Round 5
// baseline (1277.285 us; speedup 1.0000x reference)
//
#include <hip/hip_runtime.h>
#include <hip/hip_bf16.h>

#define FH 96
#define FW 96
#define NPOS (FH*FW)          // 9216
#define C 512
#define NA 9
#define NANCH (NPOS*NA)       // 82944
#define NPAD 131072           // 2^17 for bitonic
#define MAXOUT 1000
#define NMS_T 0.1f
#define TTOP 8192             // bitmask-NMS candidate window
#define MW 128                // mask words per row (TTOP/64)
#define NCELL 48
#define CCAP 8

typedef unsigned long long ull;
typedef short short8v __attribute__((ext_vector_type(8)));
typedef float f32x4 __attribute__((ext_vector_type(4)));

// dependent-chain-safe MFMA: D==C ("+v"), A/B 4-VGPR bf16x8
#define MFMA16(ACC, A, B) asm("v_mfma_f32_16x16x32_bf16 %0, %1, %2, %0" : "+v"(ACC) : "v"(A), "v"(B))

// ---------------- fp32 -> 3x bf16 split helpers (RNE) ----------------
__device__ __forceinline__ unsigned short bf16rne(float f) {
  unsigned u = __float_as_uint(f);
  return (unsigned short)((u + 0x7fffu + ((u >> 16) & 1u)) >> 16);
}
__device__ __forceinline__ float bf16tof(unsigned short h) {
  return __uint_as_float(((unsigned)h) << 16);
}
__device__ __forceinline__ void split3(float x, unsigned short& h, unsigned short& m, unsigned short& l) {
  h = bf16rne(x);
  float r1 = x - bf16tof(h);
  m = bf16rne(r1);
  float r2 = r1 - bf16tof(m);
  l = bf16rne(r2);
}

// ---------------- split feature: [9216][512] f32 -> 3 bf16 planes ----------------
__launch_bounds__(256)
__global__ void split_feat(const float* __restrict__ src,
                           unsigned short* __restrict__ hi,
                           unsigned short* __restrict__ mi,
                           unsigned short* __restrict__ lo) {
  const int i = (blockIdx.x * 256 + threadIdx.x) * 4;
  const float4 v = *(const float4*)(src + i);
  unsigned short h0,h1,h2,h3,m0,m1,m2,m3,l0,l1,l2,l3;
  split3(v.x,h0,m0,l0); split3(v.y,h1,m1,l1); split3(v.z,h2,m2,l2); split3(v.w,h3,m3,l3);
  *(ushort4*)(hi + i) = make_ushort4(h0,h1,h2,h3);
  *(ushort4*)(mi + i) = make_ushort4(m0,m1,m2,m3);
  *(ushort4*)(lo + i) = make_ushort4(l0,l1,l2,l3);
}

// ---------------- split + transpose W: [4608][512] -> 3 bf16 planes [512][4608] ----------------
__launch_bounds__(256)
__global__ void split_w(const float* __restrict__ W,
                        unsigned short* __restrict__ hi,
                        unsigned short* __restrict__ mi,
                        unsigned short* __restrict__ lo) {
  __shared__ float tile[32][36];
  const int t = threadIdx.x;
  const int k0 = blockIdx.x * 32, n0 = blockIdx.y * 32;
  {
    const int kr = t >> 3, nc = (t & 7) * 4;
    const float4 v = *(const float4*)(W + (size_t)(k0 + kr) * C + n0 + nc);
    tile[kr][nc] = v.x; tile[kr][nc+1] = v.y; tile[kr][nc+2] = v.z; tile[kr][nc+3] = v.w;
  }
  __syncthreads();
  {
    const int nr = t >> 3, kc = (t & 7) * 4;
    unsigned short h[4], m[4], l[4];
    #pragma unroll
    for (int i = 0; i < 4; ++i) split3(tile[kc + i][nr], h[i], m[i], l[i]);
    const size_t off = (size_t)(n0 + nr) * 4608 + k0 + kc;
    *(ushort4*)(hi + off) = make_ushort4(h[0],h[1],h[2],h[3]);
    *(ushort4*)(mi + off) = make_ushort4(m[0],m[1],m[2],m[3]);
    *(ushort4*)(lo + off) = make_ushort4(l[0],l[1],l[2],l[3]);
  }
}

// ---------------- Conv 3x3 via MFMA bf16x3, halo-staged (ci-outer, tap-inner) ----------------
// M-tile: 8y x 16x spatial rect (128 rows), BN=128, 8 waves of (64 rows x 32 cols).
// A-halo (10x18 positions x 32 ci x 3 splits) staged ONCE per ci-block; 9 taps read LDS.
// B (128n x 32k x 3 splits) restaged per tap, reg-prefetched under previous tap's MFMAs.
__launch_bounds__(512)
__global__ void conv_mfma(const unsigned short* __restrict__ fH,
                          const unsigned short* __restrict__ fM,
                          const unsigned short* __restrict__ fL,
                          const unsigned short* __restrict__ wH,
                          const unsigned short* __restrict__ wM,
                          const unsigned short* __restrict__ wL,
                          const float* __restrict__ br,
                          float* __restrict__ xout) {
  __shared__ __align__(16) unsigned short As[3 * 180 * 34];  // [split][hy*18+hx][34]
  __shared__ __align__(16) unsigned short Bs[3 * 128 * 34];  // [split][n][34]
  const int tid = threadIdx.x;
  const int bid = blockIdx.x;
  const int g  = bid & 3;          // n-group (XCD-aligned)
  const int tm = bid >> 2;         // m-tile 0..71
  const int ty = tm / 6, tx = tm % 6;
  const int py0 = ty * 8, px0 = tx * 16;
  const int bn = g * 128;
  const int wid = tid >> 6, lane = tid & 63;
  const int wr = wid >> 2, wc = wid & 3;   // wave tile: rows wr*64.., cols wc*32..
  const int l15 = lane & 15, lk = (lane >> 4) * 8;

  const unsigned short* fsp[3] = { fH, fM, fL };
  const unsigned short* wsp[3] = { wH, wM, wL };

  // ---- precompute A staging descriptors (5 slots: 2160 = 4*512 + 112 loads) ----
  const unsigned short* apsrc[5];
  int adst[5]; bool avalid[5];
  #pragma unroll
  for (int r = 0; r < 5; ++r) {
    const int i = tid + r * 512;
    const bool slot = (i < 2160);
    const int rowId = i >> 2, q = i & 3;
    const int s = rowId / 180, hrow = rowId % 180;
    const int hy = hrow / 18, hx = hrow % 18;
    const int gy = py0 + hy - 1, gx = px0 + hx - 1;
    const bool inb = slot && ((unsigned)gy < FH) && ((unsigned)gx < FW);
    apsrc[r]  = fsp[slot ? s : 0] + (inb ? ((size_t)(gy * FW + gx) * C + q * 8) : 0);
    adst[r]   = (s * 180 + hrow) * 34 + q * 8;
    avalid[r] = inb;
    if (!slot) adst[r] = -1;
  }
  // ---- B staging descriptors (3 slots: 1536 = 3*512) ----
  const unsigned short* bpsrc[3];
  int bdst[3];
  #pragma unroll
  for (int r = 0; r < 3; ++r) {
    const int i = tid + r * 512;
    const int rowId = i >> 2, q = i & 3;
    const int s = rowId >> 7, n = rowId & 127;
    bpsrc[r] = wsp[s] + (size_t)(bn + n) * 4608 + q * 8;
    bdst[r]  = (s * 128 + n) * 34 + q * 8;
  }

  f32x4 acc[4][2] = {};
  uint4 areg[5], breg[3];

  // ---- initial prefetch: A(ci=0), B(ci=0, tap=0) ----
  #pragma unroll
  for (int r = 0; r < 5; ++r) {
    areg[r] = make_uint4(0,0,0,0);
    if (avalid[r]) areg[r] = *(const uint4*)(apsrc[r]);
  }
  #pragma unroll
  for (int r = 0; r < 3; ++r) breg[r] = *(const uint4*)(bpsrc[r]);

  const int DY[9] = {-1,-1,-1, 0,0,0, 1,1,1};
  const int DX[9] = {-1, 0, 1,-1,0,1,-1,0,1};

  for (int ci = 0; ci < 16; ++ci) {
    __syncthreads();   // previous (ci, tap=8) LDS reads complete
    #pragma unroll
    for (int r = 0; r < 5; ++r)
      if (adst[r] >= 0) *(uint4*)&As[adst[r]] = areg[r];

    for (int tap = 0; tap < 9; ++tap) {
      #pragma unroll
      for (int r = 0; r < 3; ++r) *(uint4*)&Bs[bdst[r]] = breg[r];
      __syncthreads();  // staged

      // prefetch next B (and next A at tap boundary)
      if (tap < 8) {
        const int koff = (tap + 1) * 512 + ci * 32;
        #pragma unroll
        for (int r = 0; r < 3; ++r) breg[r] = *(const uint4*)(bpsrc[r] + koff);
      } else if (ci < 15) {
        const int coff = (ci + 1) * 32;
        #pragma unroll
        for (int r = 0; r < 5; ++r) {
          areg[r] = make_uint4(0,0,0,0);
          if (avalid[r]) areg[r] = *(const uint4*)(apsrc[r] + coff);
        }
        #pragma unroll
        for (int r = 0; r < 3; ++r) breg[r] = *(const uint4*)(bpsrc[r] + coff);
      }

      // fragment reads
      const int dy = DY[tap], dx = DX[tap];
      short8v aF[3][4], bF[3][2];
      #pragma unroll
      for (int s = 0; s < 3; ++s) {
        #pragma unroll
        for (int m = 0; m < 4; ++m) {
          const int hrow = (wr * 4 + m + 1 + dy) * 18 + (l15 + 1 + dx);
          aF[s][m] = *(const short8v*)&As[(s * 180 + hrow) * 34 + lk];
        }
        #pragma unroll
        for (int fc = 0; fc < 2; ++fc)
          bF[s][fc] = *(const short8v*)&Bs[(s * 128 + wc * 32 + fc * 16 + l15) * 34 + lk];
      }

      // 6 products x (4m x 2n) = 48 MFMA; product-outer -> 8 independent accs between reuse
      const int SA[6] = {0, 0, 1, 0, 2, 1};
      const int SB[6] = {0, 1, 0, 2, 0, 1};
      #pragma unroll
      for (int pr = 0; pr < 6; ++pr) {
        const int sa = SA[pr], sb = SB[pr];
        #pragma unroll
        for (int m = 0; m < 4; ++m)
          #pragma unroll
          for (int fc = 0; fc < 2; ++fc)
            MFMA16(acc[m][fc], aF[sa][m], bF[sb][fc]);
      }

      if (tap < 8) __syncthreads();  // frag reads done before next Bs write
    }
  }

  asm volatile("s_nop 7\ns_nop 7\ns_nop 7");

  // epilogue: C/D frag (row=(l>>4)*4+r = x-pos, col=l15 = n)
  #pragma unroll
  for (int m = 0; m < 4; ++m) {
    const int y = py0 + wr * 4 + m;
    #pragma unroll
    for (int fc = 0; fc < 2; ++fc) {
      const int col = bn + wc * 32 + fc * 16 + l15;
      const float bias = br[col];
      #pragma unroll
      for (int r = 0; r < 4; ++r) {
        const int x = px0 + (lane >> 4) * 4 + r;
        xout[(size_t)(y * FW + x) * C + col] = fmaxf(acc[m][fc][r] + bias, 0.f);
      }
    }
  }
}

// ---------------- Head: 1x1 convs + sigmoid + bbox decode + sort keys ----------------
__launch_bounds__(256)
__global__ void head_kernel(const float* __restrict__ x,
                            const float* __restrict__ Wc, const float* __restrict__ bc,
                            const float* __restrict__ Wb, const float* __restrict__ bb,
                            const float* __restrict__ anchors, const int* __restrict__ im_size,
                            float* __restrict__ scores, float* __restrict__ props,
                            ull* __restrict__ keys) {
  const int a = blockIdx.x * 256 + threadIdx.x;
  if (a >= NANCH) { if (a < NPAD) keys[a] = 0ull; return; }
  const int pos = a / NA, j = a - pos * NA;
  const float* xr = x + (size_t)pos * C;
  float accn = bc[j], accp = bc[j + NA];
  float d0 = bb[4*j], d1 = bb[4*j+1], d2 = bb[4*j+2], d3 = bb[4*j+3];
  for (int k = 0; k < C; ++k) {
    const float xv = xr[k];
    accn += xv * Wc[k * 18 + j];
    accp += xv * Wc[k * 18 + j + NA];
    const float4 wb = *(const float4*)(Wb + (size_t)k * 36 + 4 * j);
    d0 += xv * wb.x; d1 += xv * wb.y; d2 += xv * wb.z; d3 += xv * wb.w;
  }
  const float score = 1.0f / (1.0f + expf(accn - accp));
  const float4 anc = *(const float4*)(anchors + (size_t)4 * a);
  const float w  = anc.z - anc.x + 1.0f;
  const float h  = anc.w - anc.y + 1.0f;
  const float cx = anc.x + 0.5f * w;
  const float cy = anc.y + 0.5f * h;
  const float pcx = d0 * w + cx;
  const float pcy = d1 * h + cy;
  const float pw  = expf(d2) * w;
  const float ph  = expf(d3) * h;
  const float lim = (float)(*im_size - 1);
  float x1 = fminf(fmaxf(pcx - 0.5f * pw, 0.f), lim);
  float y1 = fminf(fmaxf(pcy - 0.5f * ph, 0.f), lim);
  float x2 = fminf(fmaxf(pcx + 0.5f * pw, 0.f), lim);
  float y2 = fminf(fmaxf(pcy + 0.5f * ph, 0.f), lim);
  *(float4*)(props + (size_t)4 * a) = make_float4(x1, y1, x2, y2);
  scores[a] = score;
  keys[a] = ((ull)__float_as_uint(score) << 32) | (unsigned)(~(unsigned)a);
}

// ---------------- Bitonic sort (descending), 2^17 elements ----------------
__launch_bounds__(1024)
__global__ void bitonic_local(ull* __restrict__ keys) {
  __shared__ ull s[4096];
  const int tid = threadIdx.x;
  const unsigned base = blockIdx.x * 4096u;
  for (int i = tid; i < 4096; i += 1024) s[i] = keys[base + i];
  __syncthreads();
  for (int k = 2; k <= 4096; k <<= 1) {
    for (int j = k >> 1; j > 0; j >>= 1) {
      for (int pr = tid; pr < 2048; pr += 1024) {
        const int i = ((pr / j) * 2 * j) + (pr % j);
        const int ixj = i + j;
        const bool descFirst = (((base + i) & (unsigned)k) == 0u);
        const ull av = s[i], bv = s[ixj];
        if (descFirst ? (av < bv) : (av > bv)) { s[i] = bv; s[ixj] = av; }
      }
      __syncthreads();
    }
  }
  for (int i = tid; i < 4096; i += 1024) keys[base + i] = s[i];
}

// multi-level global step: handles j = 4096<<(L-1) .. 4096 for sort-step k=4096<<L
template<int L>
__launch_bounds__(256)
__global__ void bitonic_multi(ull* __restrict__ keys, int k) {
  const int tid = blockIdx.x * 256 + threadIdx.x;   // < NPAD >> L
  const int low = tid & 4095;
  const int high = tid >> 12;
  const int base = (high << (12 + L)) | low;
  ull e[1 << L];
  #pragma unroll
  for (int m = 0; m < (1 << L); ++m) e[m] = keys[base + (m << 12)];
  const bool desc = (base & k) == 0;
  #pragma unroll
  for (int l = L - 1; l >= 0; --l) {
    #pragma unroll
    for (int m = 0; m < (1 << L); ++m) {
      if (m & (1 << l)) continue;
      const int m2 = m | (1 << l);
      const ull a = e[m], b = e[m2];
      if (desc ? (a < b) : (a > b)) { e[m] = b; e[m2] = a; }
    }
  }
  #pragma unroll
  for (int m = 0; m < (1 << L); ++m) keys[base + (m << 12)] = e[m];
}

__launch_bounds__(1024)
__global__ void bitonic_merge(ull* __restrict__ keys, int k) {
  __shared__ ull s[4096];
  const int tid = threadIdx.x;
  const unsigned base = blockIdx.x * 4096u;
  for (int i = tid; i < 4096; i += 1024) s[i] = keys[base + i];
  __syncthreads();
  const bool descFirst = ((base & (unsigned)k) == 0u);
  for (int j = 2048; j > 0; j >>= 1) {
    for (int pr = tid; pr < 2048; pr += 1024) {
      const int i = ((pr / j) * 2 * j) + (pr % j);
      const int ixj = i + j;
      const ull av = s[i], bv = s[ixj];
      if (descFirst ? (av < bv) : (av > bv)) { s[i] = bv; s[ixj] = av; }
    }
    __syncthreads();
  }
  for (int i = tid; i < 4096; i += 1024) keys[base + i] = s[i];
}

// ---------------- gather sorted top-TTOP boxes ----------------
__launch_bounds__(256)
__global__ void gather_top(const ull* __restrict__ keys, const float* __restrict__ props,
                           float4* __restrict__ sbox4, float* __restrict__ sarea,
                           int* __restrict__ sidx) {
  const int t = blockIdx.x * 256 + threadIdx.x;
  const ull key = keys[t];
  const int idx = (int)(~(unsigned)(key & 0xFFFFFFFFull));
  const float4 b = *(const float4*)(props + ((size_t)idx << 2));
  sbox4[t] = b;
  sarea[t] = (b.z - b.x) * (b.w - b.y);
  sidx[t] = idx;
}

// ---------------- mask matrix: M[i][w] bit j = IoU(sorted i, sorted w*64+j) > T, j > i ----------------
__launch_bounds__(256)
__global__ void nms_mask(const float4* __restrict__ sbox4, const float* __restrict__ sarea,
                         ull* __restrict__ M) {
  const int wb = blockIdx.x;   // word-block (4 words = 256 cols)
  const int ib = blockIdx.y;   // row-block (64 rows)
  const int tid = threadIdx.x;
  const int r = tid & 63, ww = tid >> 6;
  const int i = ib * 64 + r;
  const int w = wb * 4 + ww;
  if (wb * 4 + 3 < ib) {              // fully below diagonal: zero-fill
    M[(size_t)i * MW + w] = 0ull;
    return;
  }
  __shared__ float4 jb[256];
  __shared__ float ja[256];
  jb[tid] = sbox4[wb * 256 + tid];
  ja[tid] = sarea[wb * 256 + tid];
  __syncthreads();
  if (w < (i >> 6)) { M[(size_t)i * MW + w] = 0ull; return; }
  const float4 bi = sbox4[i];
  const float ai = sarea[i];
  ull bits = 0;
  #pragma unroll 8
  for (int jj = 0; jj < 64; ++jj) {
    const float4 bj = jb[ww * 64 + jj];
    const float ix1 = fmaxf(bi.x, bj.x), iy1 = fmaxf(bi.y, bj.y);
    const float ix2 = fminf(bi.z, bj.z), iy2 = fminf(bi.w, bj.w);
    const float inter = fmaxf(ix2 - ix1, 0.f) * fmaxf(iy2 - iy1, 0.f);
    const float iou = inter / (ai + ja[ww * 64 + jj] - inter + 1e-8f);
    bits |= (ull)(iou > NMS_T) << jj;
  }
  if (w == (i >> 6)) {
    const int b = i & 63;
    bits &= (b == 63) ? 0ull : (~0ull << (b + 1));   // keep only j > i
  }
  M[(size_t)i * MW + w] = bits;
}

// ---------------- NMS scan: bitmask walk over top-TTOP, hash fallback beyond ----------------
__launch_bounds__(1024)
__global__ void nms_scan(const ull* __restrict__ M,
                         const ull* __restrict__ keys,
                         const float4* __restrict__ sbox4,
                         const float* __restrict__ sarea,
                         const int* __restrict__ sidx,
                         const float* __restrict__ props,
                         int* __restrict__ kept_idx,
                         int* __restrict__ kept_cnt) {
  __shared__ int   s_sel[MAXOUT];
  __shared__ float kx1[MAXOUT], ky1[MAXOUT], kx2[MAXOUT], ky2[MAXOUT], kar[MAXOUT];
  __shared__ int   cellcnt[NCELL * NCELL];
  __shared__ unsigned short cellent[NCELL * NCELL * CCAP];
  __shared__ float cb[2048][5];
  __shared__ int   cidx[2048];
  __shared__ int   s_kc;
  __shared__ int   wcnt0[16], wcnt1[16];
  const int tid = threadIdx.x, wid = tid >> 6, lane = tid & 63;

  // ======== Phase A: serial bitmask scan (wave 0 only) ========
  if (tid < 64) {
    ull rm0 = 0, rm1 = 0;       // lane owns removed words 2*lane, 2*lane+1
    int kc = 0;
    for (int g = 0; g < MW && kc < MAXOUT; ++g) {
      const ull wg = __shfl((g & 1) ? rm1 : rm0, g >> 1);
      ull w = ~wg;
      while (w && kc < MAXOUT) {
        int bs[4]; int nb = 0;
        { ull wb = w;
          #pragma unroll
          for (int t = 0; t < 4; ++t) {
            bs[t] = wb ? (__ffsll((long long)wb) - 1) : 0;
            if (wb) { ++nb; wb &= wb - 1; }
          }
        }
        ulonglong2 r[4];
        #pragma unroll
        for (int t = 0; t < 4; ++t) {
          const int bb = (t < nb) ? bs[t] : bs[0];
          r[t] = *(const ulonglong2*)(M + (size_t)(g * 64 + bb) * MW + 2 * lane);
        }
        #pragma unroll
        for (int t = 0; t < 4; ++t) {
          if (t < nb && kc < MAXOUT) {
            const int b = bs[t];
            if ((w >> b) & 1ull) {
              if (lane == 0) s_sel[kc] = g * 64 + b;
              rm0 |= r[t].x; rm1 |= r[t].y;
              const ull rowg = __shfl((g & 1) ? r[t].y : r[t].x, g >> 1);
              w &= ~rowg;
              w &= ~(1ull << b);
              ++kc;
            }
          }
        }
      }
    }
    if (lane == 0) s_kc = kc;
  }
  for (int i = tid; i < NCELL * NCELL; i += 1024) cellcnt[i] = 0;
  __syncthreads();

  const int kc0 = s_kc;
  // ======== fill kept arrays + hash (parallel) ========
  for (int k = tid; k < kc0; k += 1024) {
    const int i = s_sel[k];
    const float4 b = sbox4[i];
    kx1[k] = b.x; ky1[k] = b.y; kx2[k] = b.z; ky2[k] = b.w;
    kar[k] = sarea[i];
    kept_idx[k] = sidx[i];
    if (kc0 < MAXOUT) {
      const int gx0 = (int)(b.x * 0.03125f), gxe = (int)(b.z * 0.03125f);
      const int gy0 = (int)(b.y * 0.03125f), gye = (int)(b.w * 0.03125f);
      for (int gy = gy0; gy <= gye; ++gy)
        for (int gx = gx0; gx <= gxe; ++gx) {
          const int cell = gy * NCELL + gx;
          const int o = atomicAdd(&cellcnt[cell], 1);
          if (o < CCAP) cellent[cell * CCAP + o] = (unsigned short)k;
        }
    }
  }
  __syncthreads();

  // ======== Phase C: hash-prefiltered chunks over [TTOP, NANCH) ========
  if (kc0 < MAXOUT) {
    for (int chunk = 0; chunk < 37; ++chunk) {
      __syncthreads();
      const int kcBase = s_kc;
      if (kcBase >= MAXOUT) break;
      const int base = TTOP + chunk * 2048;

      float x1a[2], y1a[2], x2a[2], y2a[2], ara[2];
      int ida[2]; bool alive[2];
      #pragma unroll
      for (int c = 0; c < 2; ++c) {
        const int ci = base + c * 1024 + tid;
        const ull key = keys[ci];
        const bool valid = (key >> 32) != 0ull;
        const int idx = (int)(~(unsigned)(key & 0xFFFFFFFFull));
        bool alv = false;
        float x1 = 0, y1 = 0, x2 = 0, y2 = 0, ar = 0;
        if (valid) {
          const float4 b = *(const float4*)(props + ((size_t)idx << 2));
          x1 = b.x; y1 = b.y; x2 = b.z; y2 = b.w;
          ar = (x2 - x1) * (y2 - y1);
          bool sup = false, fb = false;
          const int gx0 = (int)(x1 * 0.03125f), gxe = (int)(x2 * 0.03125f);
          const int gy0 = (int)(y1 * 0.03125f), gye = (int)(y2 * 0.03125f);
          for (int gy = gy0; gy <= gye; ++gy)
            for (int gx = gx0; gx <= gxe; ++gx) {
              const int cell = gy * NCELL + gx;
              int cnt = cellcnt[cell];
              fb |= (cnt > CCAP);
              cnt = min(cnt, CCAP);
              for (int e = 0; e < cnt; ++e) {
                const int kk = cellent[cell * CCAP + e];
                const float ix1 = fmaxf(x1, kx1[kk]), iy1 = fmaxf(y1, ky1[kk]);
                const float ix2 = fminf(x2, kx2[kk]), iy2 = fminf(y2, ky2[kk]);
                const float inter = fmaxf(ix2 - ix1, 0.f) * fmaxf(iy2 - iy1, 0.f);
                sup |= (inter / (ar + kar[kk] - inter + 1e-8f) > NMS_T);
              }
            }
          if (fb && !sup) {
            for (int kk = 0; kk < kcBase; ++kk) {
              const float ix1 = fmaxf(x1, kx1[kk]), iy1 = fmaxf(y1, ky1[kk]);
              const float ix2 = fminf(x2, kx2[kk]), iy2 = fminf(y2, ky2[kk]);
              const float inter = fmaxf(ix2 - ix1, 0.f) * fmaxf(iy2 - iy1, 0.f);
              sup |= (inter / (ar + kar[kk] - inter + 1e-8f) > NMS_T);
            }
          }
          alv = !sup;
        }
        x1a[c] = x1; y1a[c] = y1; x2a[c] = x2; y2a[c] = y2; ara[c] = ar;
        ida[c] = idx; alive[c] = alv;
      }
      const ull b0 = __ballot(alive[0]);
      const ull b1 = __ballot(alive[1]);
      if (lane == 0) { wcnt0[wid] = __popcll(b0); wcnt1[wid] = __popcll(b1); }
      __syncthreads();

      int tot0 = 0, pre0 = 0, pre1 = 0, tot1 = 0;
      for (int w = 0; w < 16; ++w) {
        if (w < wid) { pre0 += wcnt0[w]; pre1 += wcnt1[w]; }
        tot0 += wcnt0[w]; tot1 += wcnt1[w];
      }
      const ull ltmask = (lane == 0) ? 0ull : ((~0ull) >> (64 - lane));
      if (alive[0]) {
        const int o = pre0 + __popcll(b0 & ltmask);
        cb[o][0] = x1a[0]; cb[o][1] = y1a[0]; cb[o][2] = x2a[0]; cb[o][3] = y2a[0]; cb[o][4] = ara[0];
        cidx[o] = ida[0];
      }
      if (alive[1]) {
        const int o = tot0 + pre1 + __popcll(b1 & ltmask);
        cb[o][0] = x1a[1]; cb[o][1] = y1a[1]; cb[o][2] = x2a[1]; cb[o][3] = y2a[1]; cb[o][4] = ara[1];
        cidx[o] = ida[1];
      }
      const int n = tot0 + tot1;
      __syncthreads();

      if (tid < 64) {
        int kc = kcBase;
        for (int g = 0; g < n && kc < MAXOUT; g += 64) {
          bool alv = (g + lane) < n;
          float x1 = 0, y1 = 0, x2 = 0, y2 = 0, ar = 0;
          int idx = -1;
          if (alv) {
            x1 = cb[g + lane][0]; y1 = cb[g + lane][1];
            x2 = cb[g + lane][2]; y2 = cb[g + lane][3]; ar = cb[g + lane][4];
            idx = cidx[g + lane];
            bool sup = false;
            for (int kk = kcBase; kk < kc; ++kk) {
              const float ix1 = fmaxf(x1, kx1[kk]), iy1 = fmaxf(y1, ky1[kk]);
              const float ix2 = fminf(x2, kx2[kk]), iy2 = fminf(y2, ky2[kk]);
              const float inter = fmaxf(ix2 - ix1, 0.f) * fmaxf(iy2 - iy1, 0.f);
              sup |= (inter / (ar + kar[kk] - inter + 1e-8f) > NMS_T);
            }
            alv = alv && !sup;
          }
          while (true) {
            const ull ball = __ballot(alv);
            if (ball == 0ull || kc >= MAXOUT) break;
            const int src = __ffsll((long long)ball) - 1;
            const float bx1 = __shfl(x1, src), by1 = __shfl(y1, src);
            const float bx2 = __shfl(x2, src), by2 = __shfl(y2, src);
            const float bar = __shfl(ar, src);
            if (lane == src) {
              kx1[kc] = x1; ky1[kc] = y1; kx2[kc] = x2; ky2[kc] = y2; kar[kc] = ar;
              kept_idx[kc] = idx;
              const int gx0 = (int)(x1 * 0.03125f), gxe = (int)(x2 * 0.03125f);
              const int gy0 = (int)(y1 * 0.03125f), gye = (int)(y2 * 0.03125f);
              for (int gy = gy0; gy <= gye; ++gy)
                for (int gx = gx0; gx <= gxe; ++gx) {
                  const int cell = gy * NCELL + gx;
                  const int o = cellcnt[cell];
                  if (o < CCAP) cellent[cell * CCAP + o] = (unsigned short)kc;
                  cellcnt[cell] = o + 1;
                }
              alv = false;
            }
            if (alv) {
              const float ix1 = fmaxf(x1, bx1), iy1 = fmaxf(y1, by1);
              const float ix2 = fminf(x2, bx2), iy2 = fminf(y2, by2);
              const float inter = fmaxf(ix2 - ix1, 0.f) * fmaxf(iy2 - iy1, 0.f);
              if (inter / (ar + bar - inter + 1e-8f) > NMS_T) alv = false;
            }
            kc++;
          }
        }
        if (lane == 0) s_kc = kc;
      }
    }
  }
  __syncthreads();
  if (tid == 0) *kept_cnt = s_kc;
}

// ---------------- Output assembly ----------------
__launch_bounds__(256)
__global__ void output_kernel(const int* __restrict__ kept_idx, const int* __restrict__ kept_count,
                              const float* __restrict__ props, const float* __restrict__ scores,
                              float* __restrict__ out) {
  const int k = blockIdx.x * 256 + threadIdx.x;
  if (k >= MAXOUT) return;
  const int kc = *kept_count;
  if (k < kc) {
    const int idx = kept_idx[k];
    const float4 b = *(const float4*)(props + ((size_t)idx << 2));
    out[k * 5 + 0] = 0.f;
    out[k * 5 + 1] = b.x;
    out[k * 5 + 2] = b.y;
    out[k * 5 + 3] = b.z;
    out[k * 5 + 4] = b.w;
    out[5 * MAXOUT + k] = scores[idx];
  } else {
    out[k * 5 + 0] = 0.f;
    out[k * 5 + 1] = -1.f;
    out[k * 5 + 2] = -1.f;
    out[k * 5 + 3] = -1.f;
    out[k * 5 + 4] = -1.f;
    out[5 * MAXOUT + k] = -1.f;
  }
}

extern "C" void kernel_launch(void* const* d_in, const int* in_sizes, int n_in,
                              void* d_out, int out_size, void* d_ws, size_t ws_size,
                              hipStream_t stream) {
  const float* feat    = (const float*)d_in[0];
  const float* anchors = (const float*)d_in[1];
  const float* Wr      = (const float*)d_in[2];
  const float* br      = (const float*)d_in[3];
  const float* Wc      = (const float*)d_in[4];
  const float* bc      = (const float*)d_in[5];
  const float* Wb      = (const float*)d_in[6];
  const float* bb      = (const float*)d_in[7];
  const int*   im      = (const int*)d_in[8];
  float* out = (float*)d_out;

  char* ws = (char*)d_ws;
  // layout (max offset 64,049,152 — within proven ws capacity)
  float* x            = (float*)(ws);                     // 18,874,368
  ull*   M            = (ull*)(ws);                       // 8,388,608 (reuses x after head)
  unsigned short* fH  = (unsigned short*)(ws + 18874368); // 9,437,184 (reused below after conv)
  unsigned short* fM  = (unsigned short*)(ws + 28311552);
  unsigned short* fL  = (unsigned short*)(ws + 37748736);
  unsigned short* wH  = (unsigned short*)(ws + 47185920);
  unsigned short* wM  = (unsigned short*)(ws + 51904512);
  unsigned short* wL  = (unsigned short*)(ws + 56623104);
  float* scores       = (float*)(ws + 61341696);          // 331,776
  float* props        = (float*)(ws + 61673472);          // 1,327,104
  ull*   keys         = (ull*)  (ws + 63000576);          // 1,048,576 -> ends 64,049,152
  // overlays on dead fH region (fH dead after conv_mfma):
  float4* sbox4       = (float4*)(ws + 18874368);         // 131,072
  float*  sarea       = (float*) (ws + 19005440);         // 32,768
  int*    sidx        = (int*)   (ws + 19038208);         // 32,768
  int*    kept_idx    = (int*)   (ws + 19070976);         // 4,096
  int*    kept_cnt    = (int*)   (ws + 19075072);         // 4

  split_feat<<<4608, 256, 0, stream>>>(feat, fH, fM, fL);
  split_w<<<dim3(144, 16), 256, 0, stream>>>(Wr, wH, wM, wL);
  conv_mfma<<<288, 512, 0, stream>>>(fH, fM, fL, wH, wM, wL, br, x);
  head_kernel<<<512, 256, 0, stream>>>(x, Wc, bc, Wb, bb, anchors, im, scores, props, keys);

  bitonic_local<<<32, 1024, 0, stream>>>(keys);
  bitonic_multi<1><<<256, 256, 0, stream>>>(keys, 8192);
  bitonic_merge<<<32, 1024, 0, stream>>>(keys, 8192);
  bitonic_multi<2><<<128, 256, 0, stream>>>(keys, 16384);
  bitonic_merge<<<32, 1024, 0, stream>>>(keys, 16384);
  bitonic_multi<3><<<64, 256, 0, stream>>>(keys, 32768);
  bitonic_merge<<<32, 1024, 0, stream>>>(keys, 32768);
  bitonic_multi<4><<<32, 256, 0, stream>>>(keys, 65536);
  bitonic_merge<<<32, 1024, 0, stream>>>(keys, 65536);
  bitonic_multi<5><<<16, 256, 0, stream>>>(keys, 131072);
  bitonic_merge<<<32, 1024, 0, stream>>>(keys, 131072);

  gather_top<<<32, 256, 0, stream>>>(keys, props, sbox4, sarea, sidx);
  nms_mask<<<dim3(32, 128), 256, 0, stream>>>(sbox4, sarea, M);
  nms_scan<<<1, 1024, 0, stream>>>(M, keys, sbox4, sarea, sidx, props, kept_idx, kept_cnt);
  output_kernel<<<4, 256, 0, stream>>>(kept_idx, kept_cnt, props, scores, out);
}

// Round 6
// 1026.277 us; speedup vs baseline: 1.2446x; 1.2446x over previous
//
#include <hip/hip_runtime.h>
#include <hip/hip_bf16.h>

#define FH 96
#define FW 96
#define NPOS (FH*FW)          // 9216
#define C 512
#define NA 9
#define NANCH (NPOS*NA)       // 82944
#define NPAD 131072           // 2^17 for bitonic
#define MAXOUT 1000
#define NMS_T 0.1f
#define TTOP 8192             // bitmask-NMS candidate window
#define MW 128                // mask words per row (TTOP/64)
#define NCELL 48
#define CCAP 8

typedef unsigned long long ull;
typedef short short8v __attribute__((ext_vector_type(8)));
typedef float f32x4 __attribute__((ext_vector_type(4)));

// dependent-chain-safe MFMA: D==C ("+v"), A/B 4-VGPR bf16x8
#define MFMA16(ACC, A, B) asm("v_mfma_f32_16x16x32_bf16 %0, %1, %2, %0" : "+v"(ACC) : "v"(A), "v"(B))

// ---------------- fp32 -> 3x bf16 split helpers (RNE) ----------------
__device__ __forceinline__ unsigned short bf16rne(float f) {
  unsigned u = __float_as_uint(f);
  return (unsigned short)((u + 0x7fffu + ((u >> 16) & 1u)) >> 16);
}
__device__ __forceinline__ float bf16tof(unsigned short h) {
  return __uint_as_float(((unsigned)h) << 16);
}
__device__ __forceinline__ void split3(float x, unsigned short& h, unsigned short& m, unsigned short& l) {
  h = bf16rne(x);
  float r1 = x - bf16tof(h);
  m = bf16rne(r1);
  float r2 = r1 - bf16tof(m);
  l = bf16rne(r2);
}

// ---------------- split feature: [9216][512] f32 -> 3 bf16 planes ----------------
__launch_bounds__(256)
__global__ void split_feat(const float* __restrict__ src,
                           unsigned short* __restrict__ hi,
                           unsigned short* __restrict__ mi,
                           unsigned short* __restrict__ lo) {
  const int i = (blockIdx.x * 256 + threadIdx.x) * 4;
  const float4 v = *(const float4*)(src + i);
  unsigned short h0,h1,h2,h3,m0,m1,m2,m3,l0,l1,l2,l3;
  split3(v.x,h0,m0,l0); split3(v.y,h1,m1,l1); split3(v.z,h2,m2,l2); split3(v.w,h3,m3,l3);
  *(ushort4*)(hi + i) = make_ushort4(h0,h1,h2,h3);
  *(ushort4*)(mi + i) = make_ushort4(m0,m1,m2,m3);
  *(ushort4*)(lo + i) = make_ushort4(l0,l1,l2,l3);
}

// ---------------- split + transpose W: [4608][512] -> 3 bf16 planes [512][4608] ----------------
__launch_bounds__(256)
__global__ void split_w(const float* __restrict__ W,
                        unsigned short* __restrict__ hi,
                        unsigned short* __restrict__ mi,
                        unsigned short* __restrict__ lo) {
  __shared__ float tile[32][36];
  const int t = threadIdx.x;
  const int k0 = blockIdx.x * 32, n0 = blockIdx.y * 32;
  {
    const int kr = t >> 3, nc = (t & 7) * 4;
    const float4 v = *(const float4*)(W + (size_t)(k0 + kr) * C + n0 + nc);
    tile[kr][nc] = v.x; tile[kr][nc+1] = v.y; tile[kr][nc+2] = v.z; tile[kr][nc+3] = v.w;
  }
  __syncthreads();
  {
    const int nr = t >> 3, kc = (t & 7) * 4;
    unsigned short h[4], m[4], l[4];
    #pragma unroll
    for (int i = 0; i < 4; ++i) split3(tile[kc + i][nr], h[i], m[i], l[i]);
    const size_t off = (size_t)(n0 + nr) * 4608 + k0 + kc;
    *(ushort4*)(hi + off) = make_ushort4(h[0],h[1],h[2],h[3]);
    *(ushort4*)(mi + off) = make_ushort4(m[0],m[1],m[2],m[3]);
    *(ushort4*)(lo + off) = make_ushort4(l[0],l[1],l[2],l[3]);
  }
}

// ---------------- Conv 3x3 via MFMA bf16x3, halo-staged, 256thr/4-wave ----------------
// BM=128 (8y x 16x), BN=64, grid = 72 m-tiles x 8 n-groups = 576 blocks.
// A-halo (10x18 pos x 32 ci x 3 splits) staged once per ci-block; 9 taps read LDS.
// B (64n x 32k x 3 splits) restaged per tap, reg-prefetched under previous tap's MFMAs.
// LDS 52.7KB -> 3 blocks/CU (12 waves/CU) for latency overlap.
__launch_bounds__(256)
__global__ void conv_mfma(const unsigned short* __restrict__ fH,
                          const unsigned short* __restrict__ fM,
                          const unsigned short* __restrict__ fL,
                          const unsigned short* __restrict__ wH,
                          const unsigned short* __restrict__ wM,
                          const unsigned short* __restrict__ wL,
                          const float* __restrict__ br,
                          float* __restrict__ xout) {
  __shared__ __align__(16) unsigned short As[3 * 180 * 36];  // [split][hy*18+hx][36]
  __shared__ __align__(16) unsigned short Bs[3 * 64 * 36];   // [split][n][36]
  const int tid = threadIdx.x;
  const int bid = blockIdx.x;
  const int g  = bid & 7;          // n-group (XCD-aligned)
  const int tm = bid >> 3;         // m-tile 0..71
  const int ty = tm / 6, tx = tm % 6;
  const int py0 = ty * 8, px0 = tx * 16;
  const int bn = g * 64;
  const int wid = tid >> 6, lane = tid & 63;
  const int wr = wid >> 1, wc = wid & 1;   // wave tile: y-rows wr*4.., cols wc*32..
  const int l15 = lane & 15, lk = (lane >> 4) * 8;

  const unsigned short* fsp[3] = { fH, fM, fL };
  const unsigned short* wsp[3] = { wH, wM, wL };

  // ---- A staging descriptors (9 slots: 2160 = 8*256 + 112 uint4 loads) ----
  const unsigned short* apsrc[9];
  int adst[9]; bool avalid[9];
  #pragma unroll
  for (int r = 0; r < 9; ++r) {
    const int i = tid + r * 256;
    const bool slot = (i < 2160);
    const int rowId = (slot ? i : 0) >> 2, q = i & 3;
    const int s = rowId / 180, hrow = rowId % 180;
    const int hy = hrow / 18, hx = hrow % 18;
    const int gy = py0 + hy - 1, gx = px0 + hx - 1;
    const bool inb = slot && ((unsigned)gy < (unsigned)FH) && ((unsigned)gx < (unsigned)FW);
    apsrc[r]  = fsp[s] + (inb ? ((size_t)(gy * FW + gx) * C + q * 8) : 0);
    adst[r]   = slot ? ((s * 180 + hrow) * 36 + q * 8) : -1;
    avalid[r] = inb;
  }
  // ---- B staging descriptors (3 slots: 768 = 3*256 uint4 loads) ----
  const unsigned short* bpsrc[3];
  int bdst[3];
  #pragma unroll
  for (int r = 0; r < 3; ++r) {
    const int i = tid + r * 256;
    const int rowId = i >> 2, q = i & 3;
    const int s = rowId >> 6, n = rowId & 63;
    bpsrc[r] = wsp[s] + (size_t)(bn + n) * 4608 + q * 8;
    bdst[r]  = (s * 64 + n) * 36 + q * 8;
  }

  f32x4 acc[4][2] = {};
  uint4 areg[9], breg[3];

  // ---- initial prefetch: A(cib=0), B(cib=0, tap=0) ----
  #pragma unroll
  for (int r = 0; r < 9; ++r) {
    areg[r] = make_uint4(0,0,0,0);
    if (avalid[r]) areg[r] = *(const uint4*)(apsrc[r]);
  }
  #pragma unroll
  for (int r = 0; r < 3; ++r) breg[r] = *(const uint4*)(bpsrc[r]);

  const int DY[9] = {-1,-1,-1, 0,0,0, 1,1,1};
  const int DX[9] = {-1, 0, 1,-1,0,1,-1,0,1};

  for (int cib = 0; cib < 16; ++cib) {
    __syncthreads();   // previous (cib, tap=8) LDS reads complete
    #pragma unroll
    for (int r = 0; r < 9; ++r)
      if (adst[r] >= 0) *(uint4*)&As[adst[r]] = areg[r];

    for (int tap = 0; tap < 9; ++tap) {
      #pragma unroll
      for (int r = 0; r < 3; ++r) *(uint4*)&Bs[bdst[r]] = breg[r];
      __syncthreads();  // staged

      // prefetch next B (and next A at cib boundary) under this tap's MFMAs
      if (tap < 8) {
        const int koff = (tap + 1) * 512 + cib * 32;
        #pragma unroll
        for (int r = 0; r < 3; ++r) breg[r] = *(const uint4*)(bpsrc[r] + koff);
      } else if (cib < 15) {
        const int coff = (cib + 1) * 32;
        #pragma unroll
        for (int r = 0; r < 9; ++r) {
          areg[r] = make_uint4(0,0,0,0);
          if (avalid[r]) areg[r] = *(const uint4*)(apsrc[r] + coff);
        }
        #pragma unroll
        for (int r = 0; r < 3; ++r) breg[r] = *(const uint4*)(bpsrc[r] + coff);
      }

      // fragment reads
      const int dy = DY[tap], dx = DX[tap];
      short8v aF[3][4], bF[3][2];
      #pragma unroll
      for (int s = 0; s < 3; ++s) {
        #pragma unroll
        for (int m = 0; m < 4; ++m) {
          const int hrow = (wr * 4 + m + 1 + dy) * 18 + (l15 + 1 + dx);
          aF[s][m] = *(const short8v*)&As[(s * 180 + hrow) * 36 + lk];
        }
        #pragma unroll
        for (int fc = 0; fc < 2; ++fc)
          bF[s][fc] = *(const short8v*)&Bs[(s * 64 + wc * 32 + fc * 16 + l15) * 36 + lk];
      }

      // 6 products x (4m x 2n) = 48 MFMA; 8 independent accs between reuse
      const int SA[6] = {0, 0, 1, 0, 2, 1};
      const int SB[6] = {0, 1, 0, 2, 0, 1};
      #pragma unroll
      for (int pr = 0; pr < 6; ++pr) {
        const int sa = SA[pr], sb = SB[pr];
        #pragma unroll
        for (int m = 0; m < 4; ++m)
          #pragma unroll
          for (int fc = 0; fc < 2; ++fc)
            MFMA16(acc[m][fc], aF[sa][m], bF[sb][fc]);
      }

      if (tap < 8) __syncthreads();  // frag reads done before next Bs write
    }
  }

  asm volatile("s_nop 7\ns_nop 7\ns_nop 7");

  // epilogue: C/D frag (row=(l>>4)*4+r = x-pos, col=l15 = n)
  #pragma unroll
  for (int m = 0; m < 4; ++m) {
    const int y = py0 + wr * 4 + m;
    #pragma unroll
    for (int fc = 0; fc < 2; ++fc) {
      const int col = bn + wc * 32 + fc * 16 + l15;
      const float bias = br[col];
      #pragma unroll
      for (int r = 0; r < 4; ++r) {
        const int x = px0 + (lane >> 4) * 4 + r;
        xout[(size_t)(y * FW + x) * C + col] = fmaxf(acc[m][fc][r] + bias, 0.f);
      }
    }
  }
}

// ---------------- Head: 1x1 convs + sigmoid + bbox decode + sort keys ----------------
__launch_bounds__(256)
__global__ void head_kernel(const float* __restrict__ x,
                            const float* __restrict__ Wc, const float* __restrict__ bc,
                            const float* __restrict__ Wb, const float* __restrict__ bb,
                            const float* __restrict__ anchors, const int* __restrict__ im_size,
                            float* __restrict__ scores, float* __restrict__ props,
                            ull* __restrict__ keys) {
  const int a = blockIdx.x * 256 + threadIdx.x;
  if (a >= NANCH) { if (a < NPAD) keys[a] = 0ull; return; }
  const int pos = a / NA, j = a - pos * NA;
  const float* xr = x + (size_t)pos * C;
  float accn = bc[j], accp = bc[j + NA];
  float d0 = bb[4*j], d1 = bb[4*j+1], d2 = bb[4*j+2], d3 = bb[4*j+3];
  for (int k = 0; k < C; ++k) {
    const float xv = xr[k];
    accn += xv * Wc[k * 18 + j];
    accp += xv * Wc[k * 18 + j + NA];
    const float4 wb = *(const float4*)(Wb + (size_t)k * 36 + 4 * j);
    d0 += xv * wb.x; d1 += xv * wb.y; d2 += xv * wb.z; d3 += xv * wb.w;
  }
  const float score = 1.0f / (1.0f + expf(accn - accp));
  const float4 anc = *(const float4*)(anchors + (size_t)4 * a);
  const float w  = anc.z - anc.x + 1.0f;
  const float h  = anc.w - anc.y + 1.0f;
  const float cx = anc.x + 0.5f * w;
  const float cy = anc.y + 0.5f * h;
  const float pcx = d0 * w + cx;
  const float pcy = d1 * h + cy;
  const float pw  = expf(d2) * w;
  const float ph  = expf(d3) * h;
  const float lim = (float)(*im_size - 1);
  float x1 = fminf(fmaxf(pcx - 0.5f * pw, 0.f), lim);
  float y1 = fminf(fmaxf(pcy - 0.5f * ph, 0.f), lim);
  float x2 = fminf(fmaxf(pcx + 0.5f * pw, 0.f), lim);
  float y2 = fminf(fmaxf(pcy + 0.5f * ph, 0.f), lim);
  *(float4*)(props + (size_t)4 * a) = make_float4(x1, y1, x2, y2);
  scores[a] = score;
  keys[a] = ((ull)__float_as_uint(score) << 32) | (unsigned)(~(unsigned)a);
}

// ---------------- Bitonic sort (descending), 2^17 elements ----------------
__launch_bounds__(1024)
__global__ void bitonic_local(ull* __restrict__ keys) {
  __shared__ ull s[4096];
  const int tid = threadIdx.x;
  const unsigned base = blockIdx.x * 4096u;
  for (int i = tid; i < 4096; i += 1024) s[i] = keys[base + i];
  __syncthreads();
  for (int k = 2; k <= 4096; k <<= 1) {
    for (int j = k >> 1; j > 0; j >>= 1) {
      for (int pr = tid; pr < 2048; pr += 1024) {
        const int i = ((pr / j) * 2 * j) + (pr % j);
        const int ixj = i + j;
        const bool descFirst = (((base + i) & (unsigned)k) == 0u);
        const ull av = s[i], bv = s[ixj];
        if (descFirst ? (av < bv) : (av > bv)) { s[i] = bv; s[ixj] = av; }
      }
      __syncthreads();
    }
  }
  for (int i = tid; i < 4096; i += 1024) keys[base + i] = s[i];
}

// multi-level global step: handles j = 4096<<(L-1) .. 4096 for sort-step k=4096<<L
template<int L>
__launch_bounds__(256)
__global__ void bitonic_multi(ull* __restrict__ keys, int k) {
  const int tid = blockIdx.x * 256 + threadIdx.x;   // < NPAD >> L
  const int low = tid & 4095;
  const int high = tid >> 12;
  const int base = (high << (12 + L)) | low;
  ull e[1 << L];
  #pragma unroll
  for (int m = 0; m < (1 << L); ++m) e[m] = keys[base + (m << 12)];
  const bool desc = (base & k) == 0;
  #pragma unroll
  for (int l = L - 1; l >= 0; --l) {
    #pragma unroll
    for (int m = 0; m < (1 << L); ++m) {
      if (m & (1 << l)) continue;
      const int m2 = m | (1 << l);
      const ull a = e[m], b = e[m2];
      if (desc ? (a < b) : (a > b)) { e[m] = b; e[m2] = a; }
    }
  }
  #pragma unroll
  for (int m = 0; m < (1 << L); ++m) keys[base + (m << 12)] = e[m];
}

__launch_bounds__(1024)
__global__ void bitonic_merge(ull* __restrict__ keys, int k) {
  __shared__ ull s[4096];
  const int tid = threadIdx.x;
  const unsigned base = blockIdx.x * 4096u;
  for (int i = tid; i < 4096; i += 1024) s[i] = keys[base + i];
  __syncthreads();
  const bool descFirst = ((base & (unsigned)k) == 0u);
  for (int j = 2048; j > 0; j >>= 1) {
    for (int pr = tid; pr < 2048; pr += 1024) {
      const int i = ((pr / j) * 2 * j) + (pr % j);
      const int ixj = i + j;
      const ull av = s[i], bv = s[ixj];
      if (descFirst ? (av < bv) : (av > bv)) { s[i] = bv; s[ixj] = av; }
    }
    __syncthreads();
  }
  for (int i = tid; i < 4096; i += 1024) keys[base + i] = s[i];
}

// ---------------- gather sorted top-TTOP boxes ----------------
__launch_bounds__(256)
__global__ void gather_top(const ull* __restrict__ keys, const float* __restrict__ props,
                           float4* __restrict__ sbox4, float* __restrict__ sarea,
                           int* __restrict__ sidx) {
  const int t = blockIdx.x * 256 + threadIdx.x;
  const ull key = keys[t];
  const int idx = (int)(~(unsigned)(key & 0xFFFFFFFFull));
  const float4 b = *(const float4*)(props + ((size_t)idx << 2));
  sbox4[t] = b;
  sarea[t] = (b.z - b.x) * (b.w - b.y);
  sidx[t] = idx;
}

// ---------------- mask matrix: M[i][w] bit j = IoU(sorted i, sorted w*64+j) > T, j > i ----------------
__launch_bounds__(256)
__global__ void nms_mask(const float4* __restrict__ sbox4, const float* __restrict__ sarea,
                         ull* __restrict__ M) {
  const int wb = blockIdx.x;   // word-block (4 words = 256 cols)
  const int ib = blockIdx.y;   // row-block (64 rows)
  const int tid = threadIdx.x;
  const int r = tid & 63, ww = tid >> 6;
  const int i = ib * 64 + r;
  const int w = wb * 4 + ww;
  if (wb * 4 + 3 < ib) {              // fully below diagonal: zero-fill
    M[(size_t)i * MW + w] = 0ull;
    return;
  }
  __shared__ float4 jb[256];
  __shared__ float ja[256];
  jb[tid] = sbox4[wb * 256 + tid];
  ja[tid] = sarea[wb * 256 + tid];
  __syncthreads();
  if (w < (i >> 6)) { M[(size_t)i * MW + w] = 0ull; return; }
  const float4 bi = sbox4[i];
  const float ai = sarea[i];
  ull bits = 0;
  #pragma unroll 8
  for (int jj = 0; jj < 64; ++jj) {
    const float4 bj = jb[ww * 64 + jj];
    const float ix1 = fmaxf(bi.x, bj.x), iy1 = fmaxf(bi.y, bj.y);
    const float ix2 = fminf(bi.z, bj.z), iy2 = fminf(bi.w, bj.w);
    const float inter = fmaxf(ix2 - ix1, 0.f) * fmaxf(iy2 - iy1, 0.f);
    const float iou = inter / (ai + ja[ww * 64 + jj] - inter + 1e-8f);
    bits |= (ull)(iou > NMS_T) << jj;
  }
  if (w == (i >> 6)) {
    const int b = i & 63;
    bits &= (b == 63) ? 0ull : (~0ull << (b + 1));   // keep only j > i
  }
  M[(size_t)i * MW + w] = bits;
}

// ---------------- NMS scan: bitmask walk over top-TTOP, hash fallback beyond ----------------
__launch_bounds__(1024)
__global__ void nms_scan(const ull* __restrict__ M,
                         const ull* __restrict__ keys,
                         const float4* __restrict__ sbox4,
                         const float* __restrict__ sarea,
                         const int* __restrict__ sidx,
                         const float* __restrict__ props,
                         int* __restrict__ kept_idx,
                         int* __restrict__ kept_cnt) {
  __shared__ int   s_sel[MAXOUT];
  __shared__ float kx1[MAXOUT], ky1[MAXOUT], kx2[MAXOUT], ky2[MAXOUT], kar[MAXOUT];
  __shared__ int   cellcnt[NCELL * NCELL];
  __shared__ unsigned short cellent[NCELL * NCELL * CCAP];
  __shared__ float cb[2048][5];
  __shared__ int   cidx[2048];
  __shared__ int   s_kc;
  __shared__ int   wcnt0[16], wcnt1[16];
  const int tid = threadIdx.x, wid = tid >> 6, lane = tid & 63;

  // ======== Phase A: serial bitmask scan (wave 0 only) ========
  if (tid < 64) {
    ull rm0 = 0, rm1 = 0;       // lane owns removed words 2*lane, 2*lane+1
    int kc = 0;
    for (int g = 0; g < MW && kc < MAXOUT; ++g) {
      const ull wg = __shfl((g & 1) ? rm1 : rm0, g >> 1);
      ull w = ~wg;
      while (w && kc < MAXOUT) {
        int bs[4]; int nb = 0;
        { ull wb = w;
          #pragma unroll
          for (int t = 0; t < 4; ++t) {
            bs[t] = wb ? (__ffsll((long long)wb) - 1) : 0;
            if (wb) { ++nb; wb &= wb - 1; }
          }
        }
        ulonglong2 r[4];
        #pragma unroll
        for (int t = 0; t < 4; ++t) {
          const int bb = (t < nb) ? bs[t] : bs[0];
          r[t] = *(const ulonglong2*)(M + (size_t)(g * 64 + bb) * MW + 2 * lane);
        }
        #pragma unroll
        for (int t = 0; t < 4; ++t) {
          if (t < nb && kc < MAXOUT) {
            const int b = bs[t];
            if ((w >> b) & 1ull) {
              if (lane == 0) s_sel[kc] = g * 64 + b;
              rm0 |= r[t].x; rm1 |= r[t].y;
              const ull rowg = __shfl((g & 1) ? r[t].y : r[t].x, g >> 1);
              w &= ~rowg;
              w &= ~(1ull << b);
              ++kc;
            }
          }
        }
      }
    }
    if (lane == 0) s_kc = kc;
  }
  for (int i = tid; i < NCELL * NCELL; i += 1024) cellcnt[i] = 0;
  __syncthreads();

  const int kc0 = s_kc;
  // ======== fill kept arrays + hash (parallel) ========
  for (int k = tid; k < kc0; k += 1024) {
    const int i = s_sel[k];
    const float4 b = sbox4[i];
    kx1[k] = b.x; ky1[k] = b.y; kx2[k] = b.z; ky2[k] = b.w;
    kar[k] = sarea[i];
    kept_idx[k] = sidx[i];
    if (kc0 < MAXOUT) {
      const int gx0 = (int)(b.x * 0.03125f), gxe = (int)(b.z * 0.03125f);
      const int gy0 = (int)(b.y * 0.03125f), gye = (int)(b.w * 0.03125f);
      for (int gy = gy0; gy <= gye; ++gy)
        for (int gx = gx0; gx <= gxe; ++gx) {
          const int cell = gy * NCELL + gx;
          const int o = atomicAdd(&cellcnt[cell], 1);
          if (o < CCAP) cellent[cell * CCAP + o] = (unsigned short)k;
        }
    }
  }
  __syncthreads();

  // ======== Phase C: hash-prefiltered chunks over [TTOP, NANCH) ========
  if (kc0 < MAXOUT) {
    for (int chunk = 0; chunk < 37; ++chunk) {
      __syncthreads();
      const int kcBase = s_kc;
      if (kcBase >= MAXOUT) break;
      const int base = TTOP + chunk * 2048;

      float x1a[2], y1a[2], x2a[2], y2a[2], ara[2];
      int ida[2]; bool alive[2];
      #pragma unroll
      for (int c = 0; c < 2; ++c) {
        const int ci = base + c * 1024 + tid;
        const ull key = keys[ci];
        const bool valid = (key >> 32) != 0ull;
        const int idx = (int)(~(unsigned)(key & 0xFFFFFFFFull));
        bool alv = false;
        float x1 = 0, y1 = 0, x2 = 0, y2 = 0, ar = 0;
        if (valid) {
          const float4 b = *(const float4*)(props + ((size_t)idx << 2));
          x1 = b.x; y1 = b.y; x2 = b.z; y2 = b.w;
          ar = (x2 - x1) * (y2 - y1);
          bool sup = false, fb = false;
          const int gx0 = (int)(x1 * 0.03125f), gxe = (int)(x2 * 0.03125f);
          const int gy0 = (int)(y1 * 0.03125f), gye = (int)(y2 * 0.03125f);
          for (int gy = gy0; gy <= gye; ++gy)
            for (int gx = gx0; gx <= gxe; ++gx) {
              const int cell = gy * NCELL + gx;
              int cnt = cellcnt[cell];
              fb |= (cnt > CCAP);
              cnt = min(cnt, CCAP);
              for (int e = 0; e < cnt; ++e) {
                const int kk = cellent[cell * CCAP + e];
                const float ix1 = fmaxf(x1, kx1[kk]), iy1 = fmaxf(y1, ky1[kk]);
                const float ix2 = fminf(x2, kx2[kk]), iy2 = fminf(y2, ky2[kk]);
                const float inter = fmaxf(ix2 - ix1, 0.f) * fmaxf(iy2 - iy1, 0.f);
                sup |= (inter / (ar + kar[kk] - inter + 1e-8f) > NMS_T);
              }
            }
          if (fb && !sup) {
            for (int kk = 0; kk < kcBase; ++kk) {
              const float ix1 = fmaxf(x1, kx1[kk]), iy1 = fmaxf(y1, ky1[kk]);
              const float ix2 = fminf(x2, kx2[kk]), iy2 = fminf(y2, ky2[kk]);
              const float inter = fmaxf(ix2 - ix1, 0.f) * fmaxf(iy2 - iy1, 0.f);
              sup |= (inter / (ar + kar[kk] - inter + 1e-8f) > NMS_T);
            }
          }
          alv = !sup;
        }
        x1a[c] = x1; y1a[c] = y1; x2a[c] = x2; y2a[c] = y2; ara[c] = ar;
        ida[c] = idx; alive[c] = alv;
      }
      const ull b0 = __ballot(alive[0]);
      const ull b1 = __ballot(alive[1]);
      if (lane == 0) { wcnt0[wid] = __popcll(b0); wcnt1[wid] = __popcll(b1); }
      __syncthreads();

      int tot0 = 0, pre0 = 0, pre1 = 0, tot1 = 0;
      for (int w = 0; w < 16; ++w) {
        if (w < wid) { pre0 += wcnt0[w]; pre1 += wcnt1[w]; }
        tot0 += wcnt0[w]; tot1 += wcnt1[w];
      }
      const ull ltmask = (lane == 0) ? 0ull : ((~0ull) >> (64 - lane));
      if (alive[0]) {
        const int o = pre0 + __popcll(b0 & ltmask);
        cb[o][0] = x1a[0]; cb[o][1] = y1a[0]; cb[o][2] = x2a[0]; cb[o][3] = y2a[0]; cb[o][4] = ara[0];
        cidx[o] = ida[0];
      }
      if (alive[1]) {
        const int o = tot0 + pre1 + __popcll(b1 & ltmask);
        cb[o][0] = x1a[1]; cb[o][1] = y1a[1]; cb[o][2] = x2a[1]; cb[o][3] = y2a[1]; cb[o][4] = ara[1];
        cidx[o] = ida[1];
      }
      const int n = tot0 + tot1;
      __syncthreads();

      if (tid < 64) {
        int kc = kcBase;
        for (int g = 0; g < n && kc < MAXOUT; g += 64) {
          bool alv = (g + lane) < n;
          float x1 = 0, y1 = 0, x2 = 0, y2 = 0, ar = 0;
          int idx = -1;
          if (alv) {
            x1 = cb[g + lane][0]; y1 = cb[g + lane][1];
            x2 = cb[g + lane][2]; y2 = cb[g + lane][3]; ar = cb[g + lane][4];
            idx = cidx[g + lane];
            bool sup = false;
            for (int kk = kcBase; kk < kc; ++kk) {
              const float ix1 = fmaxf(x1, kx1[kk]), iy1 = fmaxf(y1, ky1[kk]);
              const float ix2 = fminf(x2, kx2[kk]), iy2 = fminf(y2, ky2[kk]);
              const float inter = fmaxf(ix2 - ix1, 0.f) * fmaxf(iy2 - iy1, 0.f);
              sup |= (inter / (ar + kar[kk] - inter + 1e-8f) > NMS_T);
            }
            alv = alv && !sup;
          }
          while (true) {
            const ull ball = __ballot(alv);
            if (ball == 0ull || kc >= MAXOUT) break;
            const int src = __ffsll((long long)ball) - 1;
            const float bx1 = __shfl(x1, src), by1 = __shfl(y1, src);
            const float bx2 = __shfl(x2, src), by2 = __shfl(y2, src);
            const float bar = __shfl(ar, src);
            if (lane == src) {
              kx1[kc] = x1; ky1[kc] = y1; kx2[kc] = x2; ky2[kc] = y2; kar[kc] = ar;
              kept_idx[kc] = idx;
              const int gx0 = (int)(x1 * 0.03125f), gxe = (int)(x2 * 0.03125f);
              const int gy0 = (int)(y1 * 0.03125f), gye = (int)(y2 * 0.03125f);
              for (int gy = gy0; gy <= gye; ++gy)
                for (int gx = gx0; gx <= gxe; ++gx) {
                  const int cell = gy * NCELL + gx;
                  const int o = cellcnt[cell];
                  if (o < CCAP) cellent[cell * CCAP + o] = (unsigned short)kc;
                  cellcnt[cell] = o + 1;
                }
              alv = false;
            }
            if (alv) {
              const float ix1 = fmaxf(x1, bx1), iy1 = fmaxf(y1, by1);
              const float ix2 = fminf(x2, bx2), iy2 = fminf(y2, by2);
              const float inter = fmaxf(ix2 - ix1, 0.f) * fmaxf(iy2 - iy1, 0.f);
              if (inter / (ar + bar - inter + 1e-8f) > NMS_T) alv = false;
            }
            kc++;
          }
        }
        if (lane == 0) s_kc = kc;
      }
    }
  }
  __syncthreads();
  if (tid == 0) *kept_cnt = s_kc;
}

// ---------------- Output assembly ----------------
__launch_bounds__(256)
__global__ void output_kernel(const int* __restrict__ kept_idx, const int* __restrict__ kept_count,
                              const float* __restrict__ props, const float* __restrict__ scores,
                              float* __restrict__ out) {
  const int k = blockIdx.x * 256 + threadIdx.x;
  if (k >= MAXOUT) return;
  const int kc = *kept_count;
  if (k < kc) {
    const int idx = kept_idx[k];
    const float4 b = *(const float4*)(props + ((size_t)idx << 2));
    out[k * 5 + 0] = 0.f;
    out[k * 5 + 1] = b.x;
    out[k * 5 + 2] = b.y;
    out[k * 5 + 3] = b.z;
    out[k * 5 + 4] = b.w;
    out[5 * MAXOUT + k] = scores[idx];
  } else {
    out[k * 5 + 0] = 0.f;
    out[k * 5 + 1] = -1.f;
    out[k * 5 + 2] = -1.f;
    out[k * 5 + 3] = -1.f;
    out[k * 5 + 4] = -1.f;
    out[5 * MAXOUT + k] = -1.f;
  }
}

extern "C" void kernel_launch(void* const* d_in, const int* in_sizes, int n_in,
                              void* d_out, int out_size, void* d_ws, size_t ws_size,
                              hipStream_t stream) {
  const float* feat    = (const float*)d_in[0];
  const float* anchors = (const float*)d_in[1];
  const float* Wr      = (const float*)d_in[2];
  const float* br      = (const float*)d_in[3];
  const float* Wc      = (const float*)d_in[4];
  const float* bc      = (const float*)d_in[5];
  const float* Wb      = (const float*)d_in[6];
  const float* bb      = (const float*)d_in[7];
  const int*   im      = (const int*)d_in[8];
  float* out = (float*)d_out;

  char* ws = (char*)d_ws;
  // layout (max offset 64,049,152 — within proven ws capacity)
  float* x            = (float*)(ws);                     // 18,874,368
  ull*   M            = (ull*)(ws);                       // 8,388,608 (reuses x after head)
  unsigned short* fH  = (unsigned short*)(ws + 18874368); // 9,437,184 (reused below after conv)
  unsigned short* fM  = (unsigned short*)(ws + 28311552);
  unsigned short* fL  = (unsigned short*)(ws + 37748736);
  unsigned short* wH  = (unsigned short*)(ws + 47185920);
  unsigned short* wM  = (unsigned short*)(ws + 51904512);
  unsigned short* wL  = (unsigned short*)(ws + 56623104);
  float* scores       = (float*)(ws + 61341696);          // 331,776
  float* props        = (float*)(ws + 61673472);          // 1,327,104
  ull*   keys         = (ull*)  (ws + 63000576);          // 1,048,576 -> ends 64,049,152
  // overlays on dead fH region (fH dead after conv_mfma):
  float4* sbox4       = (float4*)(ws + 18874368);         // 131,072
  float*  sarea       = (float*) (ws + 19005440);         // 32,768
  int*    sidx        = (int*)   (ws + 19038208);         // 32,768
  int*    kept_idx    = (int*)   (ws + 19070976);         // 4,096
  int*    kept_cnt    = (int*)   (ws + 19075072);         // 4

  split_feat<<<4608, 256, 0, stream>>>(feat, fH, fM, fL);
  split_w<<<dim3(144, 16), 256, 0, stream>>>(Wr, wH, wM, wL);
  conv_mfma<<<576, 256, 0, stream>>>(fH, fM, fL, wH, wM, wL, br, x);
  head_kernel<<<512, 256, 0, stream>>>(x, Wc, bc, Wb, bb, anchors, im, scores, props, keys);

  bitonic_local<<<32, 1024, 0, stream>>>(keys);
  bitonic_multi<1><<<256, 256, 0, stream>>>(keys, 8192);
  bitonic_merge<<<32, 1024, 0, stream>>>(keys, 8192);
  bitonic_multi<2><<<128, 256, 0, stream>>>(keys, 16384);
  bitonic_merge<<<32, 1024, 0, stream>>>(keys, 16384);
  bitonic_multi<3><<<64, 256, 0, stream>>>(keys, 32768);
  bitonic_merge<<<32, 1024, 0, stream>>>(keys, 32768);
  bitonic_multi<4><<<32, 256, 0, stream>>>(keys, 65536);
  bitonic_merge<<<32, 1024, 0, stream>>>(keys, 65536);
  bitonic_multi<5><<<16, 256, 0, stream>>>(keys, 131072);
  bitonic_merge<<<32, 1024, 0, stream>>>(keys, 131072);

  gather_top<<<32, 256, 0, stream>>>(keys, props, sbox4, sarea, sidx);
  nms_mask<<<dim3(32, 128), 256, 0, stream>>>(sbox4, sarea, M);
  nms_scan<<<1, 1024, 0, stream>>>(M, keys, sbox4, sarea, sidx, props, kept_idx, kept_cnt);
  output_kernel<<<4, 256, 0, stream>>>(kept_idx, kept_cnt, props, scores, out);
}

// Round 7
// 778.570 us; speedup vs baseline: 1.6406x; 1.3182x over previous
//
#include <hip/hip_runtime.h>
#include <hip/hip_bf16.h>

#define FH 96
#define FW 96
#define NPOS (FH*FW)          // 9216
#define C 512
#define NA 9
#define NANCH (NPOS*NA)       // 82944
#define NPAD 131072           // 2^17 for bitonic
#define MAXOUT 1000
#define NMS_T 0.1f
#define TTOP 8192             // bitmask-NMS candidate window
#define MW 128                // mask words per row (TTOP/64)
#define NCELL 48
#define CCAP 8

typedef unsigned long long ull;
typedef short short8v __attribute__((ext_vector_type(8)));
typedef float f32x4 __attribute__((ext_vector_type(4)));

// dependent-chain-safe MFMA: D==C ("+v"), A/B 4-VGPR bf16x8
#define MFMA16(ACC, A, B) asm("v_mfma_f32_16x16x32_bf16 %0, %1, %2, %0" : "+v"(ACC) : "v"(A), "v"(B))

// ---------------- fp32 -> 3x bf16 split helpers (RNE) ----------------
__device__ __forceinline__ unsigned short bf16rne(float f) {
  unsigned u = __float_as_uint(f);
  return (unsigned short)((u + 0x7fffu + ((u >> 16) & 1u)) >> 16);
}
__device__ __forceinline__ float bf16tof(unsigned short h) {
  return __uint_as_float(((unsigned)h) << 16);
}
__device__ __forceinline__ void split3(float x, unsigned short& h, unsigned short& m, unsigned short& l) {
  h = bf16rne(x);
  float r1 = x - bf16tof(h);
  m = bf16rne(r1);
  float r2 = r1 - bf16tof(m);
  l = bf16rne(r2);
}

// ---------------- split feature: [9216][512] f32 -> 3 bf16 planes ----------------
__launch_bounds__(256)
__global__ void split_feat(const float* __restrict__ src,
                           unsigned short* __restrict__ hi,
                           unsigned short* __restrict__ mi,
                           unsigned short* __restrict__ lo) {
  const int i = (blockIdx.x * 256 + threadIdx.x) * 4;
  const float4 v = *(const float4*)(src + i);
  unsigned short h0,h1,h2,h3,m0,m1,m2,m3,l0,l1,l2,l3;
  split3(v.x,h0,m0,l0); split3(v.y,h1,m1,l1); split3(v.z,h2,m2,l2); split3(v.w,h3,m3,l3);
  *(ushort4*)(hi + i) = make_ushort4(h0,h1,h2,h3);
  *(ushort4*)(mi + i) = make_ushort4(m0,m1,m2,m3);
  *(ushort4*)(lo + i) = make_ushort4(l0,l1,l2,l3);
}

// ---------------- split W directly to MFMA-fragment layout ----------------
// wf chunk CH = ((((g*16+cib)*9+tap)*3+s)*4+cg)*64 + lane ; wf[CH*8 + j] =
//   split_s( W[k = tap*512+cib*32+(lane>>4)*8+j][n = g*64+cg*16+(lane&15)] )
__launch_bounds__(256)
__global__ void split_w(const float* __restrict__ W,
                        unsigned short* __restrict__ wf) {
  __shared__ float tile[32][33];
  const int t = threadIdx.x;
  const int kb = blockIdx.x;            // K0 = kb*32, kb in [0,144)
  const int nb = blockIdx.y;            // N0 = nb*32, nb in [0,16)
  {
    const int kr = t >> 3, nc = (t & 7) * 4;
    const float4 v = *(const float4*)(W + (size_t)(kb * 32 + kr) * C + nb * 32 + nc);
    tile[kr][nc] = v.x; tile[kr][nc+1] = v.y; tile[kr][nc+2] = v.z; tile[kr][nc+3] = v.w;
  }
  __syncthreads();
  if (t < 128) {
    const int nl = t >> 2, kc = t & 3;
    const int n = nb * 32 + nl;
    const int tap = kb / 16, cib = kb % 16;
    const int g = n >> 6, cg = (n >> 4) & 3, lane = kc * 16 + (n & 15);
    unsigned short h[8], m[8], l[8];
    #pragma unroll
    for (int j = 0; j < 8; ++j) split3(tile[kc * 8 + j][nl], h[j], m[j], l[j]);
    const size_t base = (size_t)((((g * 16 + cib) * 9 + tap) * 3 * 4 + cg) * 64 + lane) * 8;
    uint4 uh, um, ul;
    uh.x = h[0] | ((unsigned)h[1] << 16); uh.y = h[2] | ((unsigned)h[3] << 16);
    uh.z = h[4] | ((unsigned)h[5] << 16); uh.w = h[6] | ((unsigned)h[7] << 16);
    um.x = m[0] | ((unsigned)m[1] << 16); um.y = m[2] | ((unsigned)m[3] << 16);
    um.z = m[4] | ((unsigned)m[5] << 16); um.w = m[6] | ((unsigned)m[7] << 16);
    ul.x = l[0] | ((unsigned)l[1] << 16); ul.y = l[2] | ((unsigned)l[3] << 16);
    ul.z = l[4] | ((unsigned)l[5] << 16); ul.w = l[6] | ((unsigned)l[7] << 16);
    *(uint4*)(wf + base)        = uh;   // s = 0
    *(uint4*)(wf + base + 2048) = um;   // s = 1 (stride 4*512)
    *(uint4*)(wf + base + 4096) = ul;   // s = 2
  }
}

// ---------------- Conv 3x3 via MFMA bf16x3: A-halo LDS, B fragment-direct ----------------
// BM=128 (8y x 16x), BN=64, grid = 72 m-tiles x 8 n-groups = 576. 4 waves.
// As (pitch 40 = 80B, 16-aligned) staged once per ci-block; 2 barriers/cib = 32 total.
// B fragments loaded per tap directly from wf (L2-resident per-XCD panel).
__launch_bounds__(256)
__global__ void conv_mfma(const unsigned short* __restrict__ fH,
                          const unsigned short* __restrict__ fM,
                          const unsigned short* __restrict__ fL,
                          const unsigned short* __restrict__ wf,
                          const float* __restrict__ br,
                          float* __restrict__ xout) {
  __shared__ __align__(16) unsigned short As[3 * 180 * 40];   // 43,200 B; reused as Cs fp32[128][66]
  const int tid = threadIdx.x;
  const int bid = blockIdx.x;
  const int g  = bid & 7;          // n-group (XCD-aligned)
  const int tm = bid >> 3;         // m-tile 0..71
  const int ty = tm / 6, tx = tm % 6;
  const int py0 = ty * 8, px0 = tx * 16;
  const int bn = g * 64;
  const int wid = tid >> 6, lane = tid & 63;
  const int wr = wid >> 1, wc = wid & 1;
  const int l15 = lane & 15, lk = (lane >> 4) * 8;

  const unsigned short* fsp[3] = { fH, fM, fL };

  // ---- A staging descriptors (9 slots: 2160 uint4 loads) ----
  const unsigned short* apsrc[9];
  int adst[9]; bool avalid[9];
  #pragma unroll
  for (int r = 0; r < 9; ++r) {
    const int i = tid + r * 256;
    const bool slot = (i < 2160);
    const int rowId = (slot ? i : 0) >> 2, q = i & 3;
    const int s = rowId / 180, hrow = rowId % 180;
    const int hy = hrow / 18, hx = hrow % 18;
    const int gy = py0 + hy - 1, gx = px0 + hx - 1;
    const bool inb = slot && ((unsigned)gy < (unsigned)FH) && ((unsigned)gx < (unsigned)FW);
    apsrc[r]  = fsp[s] + (inb ? ((size_t)(gy * FW + gx) * C + q * 8) : 0);
    adst[r]   = slot ? ((s * 180 + hrow) * 40 + q * 8) : -1;
    avalid[r] = inb;
  }

  // ---- B fragment base pointer (per (cib,tap,s,fc): + cib*55296 + tap*6144 + s*2048 + fc*512) ----
  const unsigned short* wfb = wf + (size_t)g * 884736 + (size_t)(wc * 2) * 512 + (size_t)lane * 8;

  f32x4 acc[4][2] = {};
  uint4 areg[9];
  #pragma unroll
  for (int r = 0; r < 9; ++r) {
    areg[r] = make_uint4(0,0,0,0);
    if (avalid[r]) areg[r] = *(const uint4*)(apsrc[r]);
  }

  for (int cib = 0; cib < 16; ++cib) {
    __syncthreads();   // previous cib's As readers done
    #pragma unroll
    for (int r = 0; r < 9; ++r)
      if (adst[r] >= 0) *(uint4*)&As[adst[r]] = areg[r];
    __syncthreads();   // As staged

    for (int tap = 0; tap < 9; ++tap) {
      // B fragment loads (L2) — issued first so latency hides under ds_reads
      short8v bF[3][2];
      const unsigned short* wt = wfb + cib * 55296 + tap * 6144;
      #pragma unroll
      for (int s = 0; s < 3; ++s)
        #pragma unroll
        for (int fc = 0; fc < 2; ++fc)
          bF[s][fc] = *(const short8v*)(wt + s * 2048 + fc * 512);

      // A prefetch for next cib, issued mid-cib (4 taps of cover)
      if (tap == 5 && cib < 15) {
        const int coff = (cib + 1) * 32;
        #pragma unroll
        for (int r = 0; r < 9; ++r) {
          areg[r] = make_uint4(0,0,0,0);
          if (avalid[r]) areg[r] = *(const uint4*)(apsrc[r] + coff);
        }
      }

      const int dy = tap / 3 - 1, dx = tap % 3 - 1;
      short8v aF[3][4];
      #pragma unroll
      for (int s = 0; s < 3; ++s)
        #pragma unroll
        for (int m = 0; m < 4; ++m) {
          const int hrow = (wr * 4 + m + 1 + dy) * 18 + (l15 + 1 + dx);
          aF[s][m] = *(const short8v*)&As[(s * 180 + hrow) * 40 + lk];
        }

      const int SA[6] = {0, 0, 1, 0, 2, 1};
      const int SB[6] = {0, 1, 0, 2, 0, 1};
      __builtin_amdgcn_s_setprio(1);
      #pragma unroll
      for (int pr = 0; pr < 6; ++pr) {
        const int sa = SA[pr], sb = SB[pr];
        #pragma unroll
        for (int m = 0; m < 4; ++m)
          #pragma unroll
          for (int fc = 0; fc < 2; ++fc)
            MFMA16(acc[m][fc], aF[sa][m], bF[sb][fc]);
      }
      __builtin_amdgcn_s_setprio(0);
    }
  }

  asm volatile("s_nop 7\ns_nop 7\ns_nop 7");

  // ---- epilogue: bias+relu -> LDS -> coalesced 256B row stores ----
  __syncthreads();   // all MFMA As reads done before reuse
  float* Cs = (float*)As;
  #pragma unroll
  for (int m = 0; m < 4; ++m)
    #pragma unroll
    for (int fc = 0; fc < 2; ++fc) {
      const int colloc = wc * 32 + fc * 16 + l15;
      const float bias = br[bn + colloc];
      #pragma unroll
      for (int r = 0; r < 4; ++r) {
        const int p = (wr * 4 + m) * 16 + (lane >> 4) * 4 + r;
        Cs[p * 66 + colloc] = fmaxf(acc[m][fc][r] + bias, 0.f);
      }
    }
  __syncthreads();
  for (int rr = 0; rr < 32; ++rr) {
    const int p = wid * 32 + rr;
    const int y = py0 + (p >> 4), x = px0 + (p & 15);
    xout[(size_t)(y * FW + x) * C + bn + lane] = Cs[p * 66 + lane];
  }
}

// ---------------- Head: LDS-staged x rows; 1x1 convs + decode + sort keys ----------------
#define HP 28
__launch_bounds__(256)
__global__ void head_kernel(const float* __restrict__ x,
                            const float* __restrict__ Wc, const float* __restrict__ bc,
                            const float* __restrict__ Wb, const float* __restrict__ bb,
                            const float* __restrict__ anchors, const int* __restrict__ im_size,
                            float* __restrict__ scores, float* __restrict__ props,
                            ull* __restrict__ keys) {
  __shared__ float xs[HP * 516];
  const int t = threadIdx.x;
  const int p0 = blockIdx.x * HP;
  #pragma unroll
  for (int ii = 0; ii < 14; ++ii) {
    const int i = t + ii * 256;        // < 3584
    const int flat = i * 4;
    const int row = flat >> 9, col = flat & 511;
    if (p0 + row < NPOS) {
      const float4 v = *(const float4*)(x + (size_t)(p0 + row) * C + col);
      *(float4*)&xs[row * 516 + col] = v;
    }
  }
  __syncthreads();
  if (t >= 252) return;
  const int pl = t / 9;
  const int pos = p0 + pl;
  if (pos >= NPOS) return;
  const int j = t - pl * 9;
  const float* xr = &xs[pl * 516];

  float accn = bc[j], accp = bc[j + NA];
  float d0 = bb[4*j], d1 = bb[4*j+1], d2 = bb[4*j+2], d3 = bb[4*j+3];
  #pragma unroll 4
  for (int k = 0; k < C; ++k) {
    const float xv = xr[k];
    accn += xv * Wc[k * 18 + j];
    accp += xv * Wc[k * 18 + j + NA];
    const float4 wb = *(const float4*)(Wb + (size_t)k * 36 + 4 * j);
    d0 += xv * wb.x; d1 += xv * wb.y; d2 += xv * wb.z; d3 += xv * wb.w;
  }
  const int a = pos * 9 + j;
  const float score = 1.0f / (1.0f + expf(accn - accp));
  const float4 anc = *(const float4*)(anchors + (size_t)4 * a);
  const float w  = anc.z - anc.x + 1.0f;
  const float h  = anc.w - anc.y + 1.0f;
  const float cx = anc.x + 0.5f * w;
  const float cy = anc.y + 0.5f * h;
  const float pcx = d0 * w + cx;
  const float pcy = d1 * h + cy;
  const float pw  = expf(d2) * w;
  const float ph  = expf(d3) * h;
  const float lim = (float)(*im_size - 1);
  float x1 = fminf(fmaxf(pcx - 0.5f * pw, 0.f), lim);
  float y1 = fminf(fmaxf(pcy - 0.5f * ph, 0.f), lim);
  float x2 = fminf(fmaxf(pcx + 0.5f * pw, 0.f), lim);
  float y2 = fminf(fmaxf(pcy + 0.5f * ph, 0.f), lim);
  *(float4*)(props + (size_t)4 * a) = make_float4(x1, y1, x2, y2);
  scores[a] = score;
  keys[a] = ((ull)__float_as_uint(score) << 32) | (unsigned)(~(unsigned)a);
}

// ---------------- Bitonic sort (descending), 2^17 elements ----------------
__launch_bounds__(1024)
__global__ void bitonic_local(ull* __restrict__ keys) {
  __shared__ ull s[4096];
  const int tid = threadIdx.x;
  const unsigned base = blockIdx.x * 4096u;
  for (int i = tid; i < 4096; i += 1024) {
    const unsigned gi = base + i;
    s[i] = (gi < NANCH) ? keys[gi] : 0ull;   // synthesize pad keys
  }
  __syncthreads();
  for (int k = 2; k <= 4096; k <<= 1) {
    for (int j = k >> 1; j > 0; j >>= 1) {
      for (int pr = tid; pr < 2048; pr += 1024) {
        const int i = ((pr / j) * 2 * j) + (pr % j);
        const int ixj = i + j;
        const bool descFirst = (((base + i) & (unsigned)k) == 0u);
        const ull av = s[i], bv = s[ixj];
        if (descFirst ? (av < bv) : (av > bv)) { s[i] = bv; s[ixj] = av; }
      }
      __syncthreads();
    }
  }
  for (int i = tid; i < 4096; i += 1024) keys[base + i] = s[i];
}

// multi-level global step: handles j = 4096<<(L-1) .. 4096 for sort-step k=4096<<L
template<int L>
__launch_bounds__(256)
__global__ void bitonic_multi(ull* __restrict__ keys, int k) {
  const int tid = blockIdx.x * 256 + threadIdx.x;   // < NPAD >> L
  const int low = tid & 4095;
  const int high = tid >> 12;
  const int base = (high << (12 + L)) | low;
  ull e[1 << L];
  #pragma unroll
  for (int m = 0; m < (1 << L); ++m) e[m] = keys[base + (m << 12)];
  const bool desc = (base & k) == 0;
  #pragma unroll
  for (int l = L - 1; l >= 0; --l) {
    #pragma unroll
    for (int m = 0; m < (1 << L); ++m) {
      if (m & (1 << l)) continue;
      const int m2 = m | (1 << l);
      const ull a = e[m], b = e[m2];
      if (desc ? (a < b) : (a > b)) { e[m] = b; e[m2] = a; }
    }
  }
  #pragma unroll
  for (int m = 0; m < (1 << L); ++m) keys[base + (m << 12)] = e[m];
}

__launch_bounds__(1024)
__global__ void bitonic_merge(ull* __restrict__ keys, int k) {
  __shared__ ull s[4096];
  const int tid = threadIdx.x;
  const unsigned base = blockIdx.x * 4096u;
  for (int i = tid; i < 4096; i += 1024) s[i] = keys[base + i];
  __syncthreads();
  const bool descFirst = ((base & (unsigned)k) == 0u);
  for (int j = 2048; j > 0; j >>= 1) {
    for (int pr = tid; pr < 2048; pr += 1024) {
      const int i = ((pr / j) * 2 * j) + (pr % j);
      const int ixj = i + j;
      const ull av = s[i], bv = s[ixj];
      if (descFirst ? (av < bv) : (av > bv)) { s[i] = bv; s[ixj] = av; }
    }
    __syncthreads();
  }
  for (int i = tid; i < 4096; i += 1024) keys[base + i] = s[i];
}

// ---------------- gather sorted top-TTOP boxes ----------------
__launch_bounds__(256)
__global__ void gather_top(const ull* __restrict__ keys, const float* __restrict__ props,
                           float4* __restrict__ sbox4, float* __restrict__ sarea,
                           int* __restrict__ sidx) {
  const int t = blockIdx.x * 256 + threadIdx.x;
  const ull key = keys[t];
  const int idx = (int)(~(unsigned)(key & 0xFFFFFFFFull));
  const float4 b = *(const float4*)(props + ((size_t)idx << 2));
  sbox4[t] = b;
  sarea[t] = (b.z - b.x) * (b.w - b.y);
  sidx[t] = idx;
}

// ---------------- mask matrix ----------------
__launch_bounds__(256)
__global__ void nms_mask(const float4* __restrict__ sbox4, const float* __restrict__ sarea,
                         ull* __restrict__ M) {
  const int wb = blockIdx.x;   // word-block (4 words = 256 cols)
  const int ib = blockIdx.y;   // row-block (64 rows)
  const int tid = threadIdx.x;
  const int r = tid & 63, ww = tid >> 6;
  const int i = ib * 64 + r;
  const int w = wb * 4 + ww;
  if (wb * 4 + 3 < ib) {
    M[(size_t)i * MW + w] = 0ull;
    return;
  }
  __shared__ float4 jb[256];
  __shared__ float ja[256];
  jb[tid] = sbox4[wb * 256 + tid];
  ja[tid] = sarea[wb * 256 + tid];
  __syncthreads();
  if (w < (i >> 6)) { M[(size_t)i * MW + w] = 0ull; return; }
  const float4 bi = sbox4[i];
  const float ai = sarea[i];
  ull bits = 0;
  #pragma unroll 8
  for (int jj = 0; jj < 64; ++jj) {
    const float4 bj = jb[ww * 64 + jj];
    const float ix1 = fmaxf(bi.x, bj.x), iy1 = fmaxf(bi.y, bj.y);
    const float ix2 = fminf(bi.z, bj.z), iy2 = fminf(bi.w, bj.w);
    const float inter = fmaxf(ix2 - ix1, 0.f) * fmaxf(iy2 - iy1, 0.f);
    const float iou = inter / (ai + ja[ww * 64 + jj] - inter + 1e-8f);
    bits |= (ull)(iou > NMS_T) << jj;
  }
  if (w == (i >> 6)) {
    const int b = i & 63;
    bits &= (b == 63) ? 0ull : (~0ull << (b + 1));
  }
  M[(size_t)i * MW + w] = bits;
}

// ---------------- NMS scan ----------------
__launch_bounds__(1024)
__global__ void nms_scan(const ull* __restrict__ M,
                         const ull* __restrict__ keys,
                         const float4* __restrict__ sbox4,
                         const float* __restrict__ sarea,
                         const int* __restrict__ sidx,
                         const float* __restrict__ props,
                         int* __restrict__ kept_idx,
                         int* __restrict__ kept_cnt) {
  __shared__ int   s_sel[MAXOUT];
  __shared__ float kx1[MAXOUT], ky1[MAXOUT], kx2[MAXOUT], ky2[MAXOUT], kar[MAXOUT];
  __shared__ int   cellcnt[NCELL * NCELL];
  __shared__ unsigned short cellent[NCELL * NCELL * CCAP];
  __shared__ float cb[2048][5];
  __shared__ int   cidx[2048];
  __shared__ int   s_kc;
  __shared__ int   wcnt0[16], wcnt1[16];
  const int tid = threadIdx.x, wid = tid >> 6, lane = tid & 63;

  // ======== Phase A: serial bitmask scan (wave 0), 8-row batched ========
  if (tid < 64) {
    ull rm0 = 0, rm1 = 0;
    int kc = 0;
    for (int g = 0; g < MW && kc < MAXOUT; ++g) {
      const ull wg = __shfl((g & 1) ? rm1 : rm0, g >> 1);
      ull w = ~wg;
      while (w && kc < MAXOUT) {
        int bs[8]; int nb = 0;
        { ull wb = w;
          #pragma unroll
          for (int t = 0; t < 8; ++t) {
            bs[t] = wb ? (__ffsll((long long)wb) - 1) : 0;
            if (wb) { ++nb; wb &= wb - 1; }
          }
        }
        ulonglong2 r[8];
        #pragma unroll
        for (int t = 0; t < 8; ++t) {
          const int bb = (t < nb) ? bs[t] : bs[0];
          r[t] = *(const ulonglong2*)(M + (size_t)(g * 64 + bb) * MW + 2 * lane);
        }
        #pragma unroll
        for (int t = 0; t < 8; ++t) {
          if (t < nb && kc < MAXOUT) {
            const int b = bs[t];
            if ((w >> b) & 1ull) {
              if (lane == 0) s_sel[kc] = g * 64 + b;
              rm0 |= r[t].x; rm1 |= r[t].y;
              const ull rowg = __shfl((g & 1) ? r[t].y : r[t].x, g >> 1);
              w &= ~rowg;
              w &= ~(1ull << b);
              ++kc;
            }
          }
        }
      }
    }
    if (lane == 0) s_kc = kc;
  }
  for (int i = tid; i < NCELL * NCELL; i += 1024) cellcnt[i] = 0;
  __syncthreads();

  const int kc0 = s_kc;
  for (int k = tid; k < kc0; k += 1024) {
    const int i = s_sel[k];
    const float4 b = sbox4[i];
    kx1[k] = b.x; ky1[k] = b.y; kx2[k] = b.z; ky2[k] = b.w;
    kar[k] = sarea[i];
    kept_idx[k] = sidx[i];
    if (kc0 < MAXOUT) {
      const int gx0 = (int)(b.x * 0.03125f), gxe = (int)(b.z * 0.03125f);
      const int gy0 = (int)(b.y * 0.03125f), gye = (int)(b.w * 0.03125f);
      for (int gy = gy0; gy <= gye; ++gy)
        for (int gx = gx0; gx <= gxe; ++gx) {
          const int cell = gy * NCELL + gx;
          const int o = atomicAdd(&cellcnt[cell], 1);
          if (o < CCAP) cellent[cell * CCAP + o] = (unsigned short)k;
        }
    }
  }
  __syncthreads();

  // ======== Phase C: hash-prefiltered chunks over [TTOP, NANCH) ========
  if (kc0 < MAXOUT) {
    for (int chunk = 0; chunk < 37; ++chunk) {
      __syncthreads();
      const int kcBase = s_kc;
      if (kcBase >= MAXOUT) break;
      const int base = TTOP + chunk * 2048;

      float x1a[2], y1a[2], x2a[2], y2a[2], ara[2];
      int ida[2]; bool alive[2];
      #pragma unroll
      for (int c = 0; c < 2; ++c) {
        const int ci = base + c * 1024 + tid;
        const ull key = keys[ci];
        const bool valid = (key >> 32) != 0ull;
        const int idx = (int)(~(unsigned)(key & 0xFFFFFFFFull));
        bool alv = false;
        float x1 = 0, y1 = 0, x2 = 0, y2 = 0, ar = 0;
        if (valid) {
          const float4 b = *(const float4*)(props + ((size_t)idx << 2));
          x1 = b.x; y1 = b.y; x2 = b.z; y2 = b.w;
          ar = (x2 - x1) * (y2 - y1);
          bool sup = false, fb = false;
          const int gx0 = (int)(x1 * 0.03125f), gxe = (int)(x2 * 0.03125f);
          const int gy0 = (int)(y1 * 0.03125f), gye = (int)(y2 * 0.03125f);
          for (int gy = gy0; gy <= gye; ++gy)
            for (int gx = gx0; gx <= gxe; ++gx) {
              const int cell = gy * NCELL + gx;
              int cnt = cellcnt[cell];
              fb |= (cnt > CCAP);
              cnt = min(cnt, CCAP);
              for (int e = 0; e < cnt; ++e) {
                const int kk = cellent[cell * CCAP + e];
                const float ix1 = fmaxf(x1, kx1[kk]), iy1 = fmaxf(y1, ky1[kk]);
                const float ix2 = fminf(x2, kx2[kk]), iy2 = fminf(y2, ky2[kk]);
                const float inter = fmaxf(ix2 - ix1, 0.f) * fmaxf(iy2 - iy1, 0.f);
                sup |= (inter / (ar + kar[kk] - inter + 1e-8f) > NMS_T);
              }
            }
          if (fb && !sup) {
            for (int kk = 0; kk < kcBase; ++kk) {
              const float ix1 = fmaxf(x1, kx1[kk]), iy1 = fmaxf(y1, ky1[kk]);
              const float ix2 = fminf(x2, kx2[kk]), iy2 = fminf(y2, ky2[kk]);
              const float inter = fmaxf(ix2 - ix1, 0.f) * fmaxf(iy2 - iy1, 0.f);
              sup |= (inter / (ar + kar[kk] - inter + 1e-8f) > NMS_T);
            }
          }
          alv = !sup;
        }
        x1a[c] = x1; y1a[c] = y1; x2a[c] = x2; y2a[c] = y2; ara[c] = ar;
        ida[c] = idx; alive[c] = alv;
      }
      const ull b0 = __ballot(alive[0]);
      const ull b1 = __ballot(alive[1]);
      if (lane == 0) { wcnt0[wid] = __popcll(b0); wcnt1[wid] = __popcll(b1); }
      __syncthreads();

      int tot0 = 0, pre0 = 0, pre1 = 0, tot1 = 0;
      for (int w = 0; w < 16; ++w) {
        if (w < wid) { pre0 += wcnt0[w]; pre1 += wcnt1[w]; }
        tot0 += wcnt0[w]; tot1 += wcnt1[w];
      }
      const ull ltmask = (lane == 0) ? 0ull : ((~0ull) >> (64 - lane));
      if (alive[0]) {
        const int o = pre0 + __popcll(b0 & ltmask);
        cb[o][0] = x1a[0]; cb[o][1] = y1a[0]; cb[o][2] = x2a[0]; cb[o][3] = y2a[0]; cb[o][4] = ara[0];
        cidx[o] = ida[0];
      }
      if (alive[1]) {
        const int o = tot0 + pre1 + __popcll(b1 & ltmask);
        cb[o][0] = x1a[1]; cb[o][1] = y1a[1]; cb[o][2] = x2a[1]; cb[o][3] = y2a[1]; cb[o][4] = ara[1];
        cidx[o] = ida[1];
      }
      const int n = tot0 + tot1;
      __syncthreads();

      if (tid < 64) {
        int kc = kcBase;
        for (int g = 0; g < n && kc < MAXOUT; g += 64) {
          bool alv = (g + lane) < n;
          float x1 = 0, y1 = 0, x2 = 0, y2 = 0, ar = 0;
          int idx = -1;
          if (alv) {
            x1 = cb[g + lane][0]; y1 = cb[g + lane][1];
            x2 = cb[g + lane][2]; y2 = cb[g + lane][3]; ar = cb[g + lane][4];
            idx = cidx[g + lane];
            bool sup = false;
            for (int kk = kcBase; kk < kc; ++kk) {
              const float ix1 = fmaxf(x1, kx1[kk]), iy1 = fmaxf(y1, ky1[kk]);
              const float ix2 = fminf(x2, kx2[kk]), iy2 = fminf(y2, ky2[kk]);
              const float inter = fmaxf(ix2 - ix1, 0.f) * fmaxf(iy2 - iy1, 0.f);
              sup |= (inter / (ar + kar[kk] - inter + 1e-8f) > NMS_T);
            }
            alv = alv && !sup;
          }
          while (true) {
            const ull ball = __ballot(alv);
            if (ball == 0ull || kc >= MAXOUT) break;
            const int src = __ffsll((long long)ball) - 1;
            const float bx1 = __shfl(x1, src), by1 = __shfl(y1, src);
            const float bx2 = __shfl(x2, src), by2 = __shfl(y2, src);
            const float bar = __shfl(ar, src);
            if (lane == src) {
              kx1[kc] = x1; ky1[kc] = y1; kx2[kc] = x2; ky2[kc] = y2; kar[kc] = ar;
              kept_idx[kc] = idx;
              const int gx0 = (int)(x1 * 0.03125f), gxe = (int)(x2 * 0.03125f);
              const int gy0 = (int)(y1 * 0.03125f), gye = (int)(y2 * 0.03125f);
              for (int gy = gy0; gy <= gye; ++gy)
                for (int gx = gx0; gx <= gxe; ++gx) {
                  const int cell = gy * NCELL + gx;
                  const int o = cellcnt[cell];
                  if (o < CCAP) cellent[cell * CCAP + o] = (unsigned short)kc;
                  cellcnt[cell] = o + 1;
                }
              alv = false;
            }
            if (alv) {
              const float ix1 = fmaxf(x1, bx1), iy1 = fmaxf(y1, by1);
              const float ix2 = fminf(x2, bx2), iy2 = fminf(y2, by2);
              const float inter = fmaxf(ix2 - ix1, 0.f) * fmaxf(iy2 - iy1, 0.f);
              if (inter / (ar + bar - inter + 1e-8f) > NMS_T) alv = false;
            }
            kc++;
          }
        }
        if (lane == 0) s_kc = kc;
      }
    }
  }
  __syncthreads();
  if (tid == 0) *kept_cnt = s_kc;
}

// ---------------- Output assembly ----------------
__launch_bounds__(256)
__global__ void output_kernel(const int* __restrict__ kept_idx, const int* __restrict__ kept_count,
                              const float* __restrict__ props, const float* __restrict__ scores,
                              float* __restrict__ out) {
  const int k = blockIdx.x * 256 + threadIdx.x;
  if (k >= MAXOUT) return;
  const int kc = *kept_count;
  if (k < kc) {
    const int idx = kept_idx[k];
    const float4 b = *(const float4*)(props + ((size_t)idx << 2));
    out[k * 5 + 0] = 0.f;
    out[k * 5 + 1] = b.x;
    out[k * 5 + 2] = b.y;
    out[k * 5 + 3] = b.z;
    out[k * 5 + 4] = b.w;
    out[5 * MAXOUT + k] = scores[idx];
  } else {
    out[k * 5 + 0] = 0.f;
    out[k * 5 + 1] = -1.f;
    out[k * 5 + 2] = -1.f;
    out[k * 5 + 3] = -1.f;
    out[k * 5 + 4] = -1.f;
    out[5 * MAXOUT + k] = -1.f;
  }
}

extern "C" void kernel_launch(void* const* d_in, const int* in_sizes, int n_in,
                              void* d_out, int out_size, void* d_ws, size_t ws_size,
                              hipStream_t stream) {
  const float* feat    = (const float*)d_in[0];
  const float* anchors = (const float*)d_in[1];
  const float* Wr      = (const float*)d_in[2];
  const float* br      = (const float*)d_in[3];
  const float* Wc      = (const float*)d_in[4];
  const float* bc      = (const float*)d_in[5];
  const float* Wb      = (const float*)d_in[6];
  const float* bb      = (const float*)d_in[7];
  const int*   im      = (const int*)d_in[8];
  float* out = (float*)d_out;

  char* ws = (char*)d_ws;
  // layout (max offset 64,049,152 — within proven ws capacity)
  float* x            = (float*)(ws);                     // 18,874,368
  ull*   M            = (ull*)(ws);                       // 8,388,608 (reuses x after head)
  unsigned short* fH  = (unsigned short*)(ws + 18874368); // 9,437,184 each
  unsigned short* fM  = (unsigned short*)(ws + 28311552);
  unsigned short* fL  = (unsigned short*)(ws + 37748736);
  unsigned short* wf  = (unsigned short*)(ws + 47185920); // 14,155,776 -> ends 61,341,696
  float* scores       = (float*)(ws + 61341696);          // 331,776
  float* props        = (float*)(ws + 61673472);          // 1,327,104
  ull*   keys         = (ull*)  (ws + 63000576);          // 1,048,576 -> ends 64,049,152
  // overlays on dead fH region (fH dead after conv_mfma):
  float4* sbox4       = (float4*)(ws + 18874368);         // 131,072
  float*  sarea       = (float*) (ws + 19005440);         // 32,768
  int*    sidx        = (int*)   (ws + 19038208);         // 32,768
  int*    kept_idx    = (int*)   (ws + 19070976);         // 4,096
  int*    kept_cnt    = (int*)   (ws + 19075072);         // 4

  split_feat<<<4608, 256, 0, stream>>>(feat, fH, fM, fL);
  split_w<<<dim3(144, 16), 256, 0, stream>>>(Wr, wf);
  conv_mfma<<<576, 256, 0, stream>>>(fH, fM, fL, wf, br, x);
  head_kernel<<<330, 256, 0, stream>>>(x, Wc, bc, Wb, bb, anchors, im, scores, props, keys);

  bitonic_local<<<32, 1024, 0, stream>>>(keys);
  bitonic_multi<1><<<256, 256, 0, stream>>>(keys, 8192);
  bitonic_merge<<<32, 1024, 0, stream>>>(keys, 8192);
  bitonic_multi<2><<<128, 256, 0, stream>>>(keys, 16384);
  bitonic_merge<<<32, 1024, 0, stream>>>(keys, 16384);
  bitonic_multi<3><<<64, 256, 0, stream>>>(keys, 32768);
  bitonic_merge<<<32, 1024, 0, stream>>>(keys, 32768);
  bitonic_multi<4><<<32, 256, 0, stream>>>(keys, 65536);
  bitonic_merge<<<32, 1024, 0, stream>>>(keys, 65536);
  bitonic_multi<5><<<16, 256, 0, stream>>>(keys, 131072);
  bitonic_merge<<<32, 1024, 0, stream>>>(keys, 131072);

  gather_top<<<32, 256, 0, stream>>>(keys, props, sbox4, sarea, sidx);
  nms_mask<<<dim3(32, 128), 256, 0, stream>>>(sbox4, sarea, M);
  nms_scan<<<1, 1024, 0, stream>>>(M, keys, sbox4, sarea, sidx, props, kept_idx, kept_cnt);
  output_kernel<<<4, 256, 0, stream>>>(kept_idx, kept_cnt, props, scores, out);
}